// Round 1
// baseline (2876.083 us; speedup 1.0000x reference)
//
#include <hip/hip_runtime.h>
#include <hip/hip_bf16.h>

#define NNODES 50000
#define NEDGES 800000
#define D 128
#define DOUT 64

// ---------------------------------------------------------------------------
// deg[i] = in-degree of node i (self-loop added later as +1)
__global__ void deg_kernel(const int* __restrict__ dst, int* __restrict__ deg) {
    int i = blockIdx.x * blockDim.x + threadIdx.x;
    if (i < NEDGES) atomicAdd(&deg[dst[i]], 1);
}

// Wa = Wpre @ W1  (128x128), ba = bpre @ W1 + b1  (128)
// blocks 0..127: one row of Wa; block 128: ba
__global__ void combine_w_kernel(const float* __restrict__ Wpre, const float* __restrict__ bpre,
                                 const float* __restrict__ W1, const float* __restrict__ b1,
                                 float* __restrict__ Wa, float* __restrict__ ba) {
    const int j = threadIdx.x;
    const int i = blockIdx.x;
    if (i < D) {
        float s = 0.0f;
        for (int k = 0; k < D; ++k) s = fmaf(Wpre[i * D + k], W1[k * D + j], s);
        Wa[i * D + j] = s;
    } else {
        float s = b1[j];
        for (int k = 0; k < D; ++k) s = fmaf(bpre[k], W1[k * D + j], s);
        ba[j] = s;
    }
}

// scatter-add src features onto dst rows: 32 threads per edge, float4 each
__global__ void scatter_kernel(const float4* __restrict__ feat,  // [N][32] float4
                               const int* __restrict__ ei,       // [2][E]
                               float* __restrict__ sum) {        // [N][128]
    int idx = blockIdx.x * blockDim.x + threadIdx.x;
    if (idx >= NEDGES * 32) return;
    const int e = idx >> 5;
    const int c = idx & 31;
    const int s = ei[e];
    const int d = ei[NEDGES + e];
    const float4 v = feat[s * 32 + c];
    float* p = &sum[d * D + c * 4];
    atomicAdd(p + 0, v.x);
    atomicAdd(p + 1, v.y);
    atomicAdd(p + 2, v.z);
    atomicAdd(p + 3, v.w);
}

// h1 = relu(((sum1 + x) / (deg+1)) @ Wa + ba)
// block: 256 thr, tile 64 rows x 128 cols, per-thread 4 rows x 8 cols
__global__ void gemm1_kernel(const float* __restrict__ sum1, const float* __restrict__ x,
                             const int* __restrict__ deg,
                             const float* __restrict__ Wa, const float* __restrict__ ba,
                             float* __restrict__ h1) {
    __shared__ float sA[64 * 132];   // padded stride 132 (16B aligned)
    __shared__ float sW[32 * 128];   // one k-quarter of Wa
    const int tid = threadIdx.x;
    const int rbase = blockIdx.x * 64;
    const int colgrp = tid & 15;
    const int rowgrp = tid >> 4;     // 0..15
    const int c0 = colgrp * 8;

    // stage A tile (scaled by 1/(deg+1))
    #pragma unroll
    for (int i = 0; i < 8; ++i) {
        const int f = tid + i * 256;          // 0..2047
        const int row = f >> 5, c4 = f & 31;
        int rg = rbase + row;
        if (rg > NNODES - 1) rg = NNODES - 1; // clamp: safe reads, stores guarded
        const float inv = 1.0f / (float)(deg[rg] + 1);
        const float4 a = *(const float4*)&sum1[rg * D + c4 * 4];
        const float4 b = *(const float4*)&x[rg * D + c4 * 4];
        float4 v;
        v.x = (a.x + b.x) * inv; v.y = (a.y + b.y) * inv;
        v.z = (a.z + b.z) * inv; v.w = (a.w + b.w) * inv;
        *(float4*)&sA[row * 132 + c4 * 4] = v;
    }

    float acc[4][8];
    #pragma unroll
    for (int r = 0; r < 4; ++r)
        #pragma unroll
        for (int j = 0; j < 8; ++j) acc[r][j] = 0.0f;

    for (int kq = 0; kq < 4; ++kq) {
        __syncthreads();   // A ready (kq=0) / previous sW consumed (kq>0)
        #pragma unroll
        for (int i = 0; i < 4; ++i) {
            const int f = tid + i * 256;       // 0..1023
            const int kr = f >> 5, c4 = f & 31;
            *(float4*)&sW[kr * 128 + c4 * 4] =
                *(const float4*)&Wa[(kq * 32 + kr) * D + c4 * 4];
        }
        __syncthreads();
        #pragma unroll
        for (int k = 0; k < 32; k += 4) {
            const int kg = kq * 32 + k;
            float a0[4], a1[4], a2[4], a3[4];
            *(float4*)a0 = *(const float4*)&sA[(rowgrp * 4 + 0) * 132 + kg];
            *(float4*)a1 = *(const float4*)&sA[(rowgrp * 4 + 1) * 132 + kg];
            *(float4*)a2 = *(const float4*)&sA[(rowgrp * 4 + 2) * 132 + kg];
            *(float4*)a3 = *(const float4*)&sA[(rowgrp * 4 + 3) * 132 + kg];
            #pragma unroll
            for (int dk = 0; dk < 4; ++dk) {
                float w[8];
                *(float4*)&w[0] = *(const float4*)&sW[(k + dk) * 128 + c0];
                *(float4*)&w[4] = *(const float4*)&sW[(k + dk) * 128 + c0 + 4];
                #pragma unroll
                for (int j = 0; j < 8; ++j) {
                    acc[0][j] = fmaf(a0[dk], w[j], acc[0][j]);
                    acc[1][j] = fmaf(a1[dk], w[j], acc[1][j]);
                    acc[2][j] = fmaf(a2[dk], w[j], acc[2][j]);
                    acc[3][j] = fmaf(a3[dk], w[j], acc[3][j]);
                }
            }
        }
    }

    #pragma unroll
    for (int r = 0; r < 4; ++r) {
        const int row = rbase + rowgrp * 4 + r;
        if (row < NNODES) {
            float o[8];
            #pragma unroll
            for (int j = 0; j < 8; ++j) {
                const float v = acc[r][j] + ba[c0 + j];
                o[j] = v > 0.0f ? v : 0.0f;
            }
            *(float4*)&h1[row * D + c0]     = *(const float4*)&o[0];
            *(float4*)&h1[row * D + c0 + 4] = *(const float4*)&o[4];
        }
    }
}

// out = rownorm(((sum2 + h1) / (deg+1)) @ W2 + b2)
// block: 256 thr, tile 64 rows x 64 cols, per-thread 2 rows x 8 cols
__global__ void gemm2_kernel(const float* __restrict__ sum2, const float* __restrict__ h1,
                             const int* __restrict__ deg,
                             const float* __restrict__ W2, const float* __restrict__ b2,
                             float* __restrict__ out) {
    __shared__ float sA[64 * 132];
    __shared__ float sW[64 * 64];    // one k-half of W2
    const int tid = threadIdx.x;
    const int rbase = blockIdx.x * 64;
    const int colgrp = tid & 7;
    const int rowgrp = tid >> 3;     // 0..31
    const int c0 = colgrp * 8;

    #pragma unroll
    for (int i = 0; i < 8; ++i) {
        const int f = tid + i * 256;
        const int row = f >> 5, c4 = f & 31;
        int rg = rbase + row;
        if (rg > NNODES - 1) rg = NNODES - 1;
        const float inv = 1.0f / (float)(deg[rg] + 1);
        const float4 a = *(const float4*)&sum2[rg * D + c4 * 4];
        const float4 b = *(const float4*)&h1[rg * D + c4 * 4];
        float4 v;
        v.x = (a.x + b.x) * inv; v.y = (a.y + b.y) * inv;
        v.z = (a.z + b.z) * inv; v.w = (a.w + b.w) * inv;
        *(float4*)&sA[row * 132 + c4 * 4] = v;
    }

    float acc[2][8];
    #pragma unroll
    for (int r = 0; r < 2; ++r)
        #pragma unroll
        for (int j = 0; j < 8; ++j) acc[r][j] = 0.0f;

    for (int kh = 0; kh < 2; ++kh) {
        __syncthreads();
        #pragma unroll
        for (int i = 0; i < 4; ++i) {
            const int f = tid + i * 256;        // 0..1023
            const int kr = f >> 4, c4 = f & 15;
            *(float4*)&sW[kr * 64 + c4 * 4] =
                *(const float4*)&W2[(kh * 64 + kr) * DOUT + c4 * 4];
        }
        __syncthreads();
        #pragma unroll
        for (int k = 0; k < 64; k += 4) {
            const int kg = kh * 64 + k;
            float a0[4], a1[4];
            *(float4*)a0 = *(const float4*)&sA[(rowgrp * 2 + 0) * 132 + kg];
            *(float4*)a1 = *(const float4*)&sA[(rowgrp * 2 + 1) * 132 + kg];
            #pragma unroll
            for (int dk = 0; dk < 4; ++dk) {
                float w[8];
                *(float4*)&w[0] = *(const float4*)&sW[(k + dk) * 64 + c0];
                *(float4*)&w[4] = *(const float4*)&sW[(k + dk) * 64 + c0 + 4];
                #pragma unroll
                for (int j = 0; j < 8; ++j) {
                    acc[0][j] = fmaf(a0[dk], w[j], acc[0][j]);
                    acc[1][j] = fmaf(a1[dk], w[j], acc[1][j]);
                }
            }
        }
    }

    // bias + L2 row-normalize (8 colgrp lanes per row are contiguous in wave)
    #pragma unroll
    for (int r = 0; r < 2; ++r) {
        const int row = rbase + rowgrp * 2 + r;
        float v[8];
        float ss = 0.0f;
        #pragma unroll
        for (int j = 0; j < 8; ++j) {
            v[j] = acc[r][j] + b2[c0 + j];
            ss = fmaf(v[j], v[j], ss);
        }
        ss += __shfl_xor(ss, 1);
        ss += __shfl_xor(ss, 2);
        ss += __shfl_xor(ss, 4);
        const float nrm = sqrtf(ss);
        const float inv = 1.0f / fmaxf(nrm, 1e-12f);
        if (row < NNODES) {
            float o[8];
            #pragma unroll
            for (int j = 0; j < 8; ++j) o[j] = v[j] * inv;
            *(float4*)&out[row * DOUT + c0]     = *(const float4*)&o[0];
            *(float4*)&out[row * DOUT + c0 + 4] = *(const float4*)&o[4];
        }
    }
}

// ---------------------------------------------------------------------------
extern "C" void kernel_launch(void* const* d_in, const int* in_sizes, int n_in,
                              void* d_out, int out_size, void* d_ws, size_t ws_size,
                              hipStream_t stream) {
    const float* x    = (const float*)d_in[0];
    const int*   ei   = (const int*)d_in[1];
    const float* Wpre = (const float*)d_in[2];
    const float* bpre = (const float*)d_in[3];
    const float* W1   = (const float*)d_in[4];
    const float* b1   = (const float*)d_in[5];
    const float* W2   = (const float*)d_in[6];
    const float* b2   = (const float*)d_in[7];
    float* out = (float*)d_out;

    // workspace layout (~51.5 MB)
    char* ws = (char*)d_ws;
    float* sum = (float*)ws;                                    // N*128 f32 = 25.6e6 B
    float* h1  = (float*)(ws + 25600000);                       // N*128 f32
    int*   deg = (int*)(ws + 51200000);                         // N i32 (200000 B)
    float* Wa  = (float*)(ws + 51200000 + 200704);              // 128*128 f32
    float* ba  = Wa + D * D;                                    // 128 f32

    hipMemsetAsync(sum, 0, (size_t)NNODES * D * sizeof(float), stream);
    hipMemsetAsync(deg, 0, (size_t)NNODES * sizeof(int), stream);

    deg_kernel<<<(NEDGES + 255) / 256, 256, 0, stream>>>(ei + NEDGES, deg);
    combine_w_kernel<<<D + 1, D, 0, stream>>>(Wpre, bpre, W1, b1, Wa, ba);

    // agg1 = A @ x
    scatter_kernel<<<(NEDGES * 32) / 256, 256, 0, stream>>>((const float4*)x, ei, sum);
    // h1 = relu(agg1 @ Wa + ba)
    gemm1_kernel<<<(NNODES + 63) / 64, 256, 0, stream>>>(sum, x, deg, Wa, ba, h1);

    // agg2 = A @ h1 (reuse sum buffer)
    hipMemsetAsync(sum, 0, (size_t)NNODES * D * sizeof(float), stream);
    scatter_kernel<<<(NEDGES * 32) / 256, 256, 0, stream>>>((const float4*)h1, ei, sum);
    // out = rownorm(agg2 @ W2 + b2)
    gemm2_kernel<<<(NNODES + 63) / 64, 256, 0, stream>>>(sum, h1, deg, W2, b2, out);
}

// Round 3
// 436.701 us; speedup vs baseline: 6.5859x; 6.5859x over previous
//
#include <hip/hip_runtime.h>
#include <hip/hip_bf16.h>

#define NNODES 50000
#define NEDGES 800000
#define D 128
#define DOUT 64

// ---------------------------------------------------------------------------
// deg[i] = in-degree of node i (self-loop handled separately as +1)
__global__ void deg_kernel(const int* __restrict__ dst, int* __restrict__ deg) {
    int i = blockIdx.x * blockDim.x + threadIdx.x;
    if (i < NEDGES) atomicAdd(&deg[dst[i]], 1);
}

// Wa = Wpre @ W1 (128x128), ba = bpre @ W1 + b1 (128)
__global__ void combine_w_kernel(const float* __restrict__ Wpre, const float* __restrict__ bpre,
                                 const float* __restrict__ W1, const float* __restrict__ b1,
                                 float* __restrict__ Wa, float* __restrict__ ba) {
    const int j = threadIdx.x;
    const int i = blockIdx.x;
    if (i < D) {
        float s = 0.0f;
        for (int k = 0; k < D; ++k) s = fmaf(Wpre[i * D + k], W1[k * D + j], s);
        Wa[i * D + j] = s;
    } else {
        float s = b1[j];
        for (int k = 0; k < D; ++k) s = fmaf(bpre[k], W1[k * D + j], s);
        ba[j] = s;
    }
}

// exclusive prefix sum of deg[50000] -> rowstart, cursor. One block, 1024 thr.
#define SCAN_CHUNK 49   // 1024*49 = 50176 >= 50000
__global__ void scan_kernel(const int* __restrict__ deg,
                            int* __restrict__ rowstart, int* __restrict__ cursor) {
    __shared__ int part[1024];
    const int t = threadIdx.x;
    const int base = t * SCAN_CHUNK;
    int s = 0;
    for (int i = 0; i < SCAN_CHUNK; ++i) {
        const int idx = base + i;
        if (idx < NNODES) s += deg[idx];
    }
    part[t] = s;
    __syncthreads();
    for (int off = 1; off < 1024; off <<= 1) {
        const int v = part[t];
        const int add = (t >= off) ? part[t - off] : 0;
        __syncthreads();
        part[t] = v + add;
        __syncthreads();
    }
    int run = (t == 0) ? 0 : part[t - 1];
    for (int i = 0; i < SCAN_CHUNK; ++i) {
        const int idx = base + i;
        if (idx < NNODES) {
            rowstart[idx] = run;
            cursor[idx] = run;
            run += deg[idx];
        }
    }
}

// bucket-fill CSR: ebuf[rowstart[dst]..] = src ids
__global__ void fill_kernel(const int* __restrict__ ei, int* __restrict__ cursor,
                            int* __restrict__ ebuf) {
    int e = blockIdx.x * blockDim.x + threadIdx.x;
    if (e < NEDGES) {
        const int d = ei[NEDGES + e];
        const int pos = atomicAdd(&cursor[d], 1);
        ebuf[pos] = ei[e];
    }
}

// ---------------------------------------------------------------------------
// y1 = x @ Wa   (tile 64 rows x 128 cols, 256 thr, 4x8 per thread)
__global__ void gemm_y1_kernel(const float* __restrict__ x, const float* __restrict__ Wa,
                               float* __restrict__ y1) {
    __shared__ float sA[64 * 132];
    __shared__ float sW[32 * 128];
    const int tid = threadIdx.x;
    const int rbase = blockIdx.x * 64;
    const int colgrp = tid & 15;
    const int rowgrp = tid >> 4;
    const int c0 = colgrp * 8;

    #pragma unroll
    for (int i = 0; i < 8; ++i) {
        const int f = tid + i * 256;
        const int row = f >> 5, c4 = f & 31;
        int rg = rbase + row;
        if (rg > NNODES - 1) rg = NNODES - 1;
        *(float4*)&sA[row * 132 + c4 * 4] = *(const float4*)&x[(size_t)rg * D + c4 * 4];
    }

    float acc[4][8];
    #pragma unroll
    for (int r = 0; r < 4; ++r)
        #pragma unroll
        for (int j = 0; j < 8; ++j) acc[r][j] = 0.0f;

    for (int kq = 0; kq < 4; ++kq) {
        __syncthreads();
        #pragma unroll
        for (int i = 0; i < 4; ++i) {
            const int f = tid + i * 256;
            const int kr = f >> 5, c4 = f & 31;
            *(float4*)&sW[kr * 128 + c4 * 4] =
                *(const float4*)&Wa[(kq * 32 + kr) * D + c4 * 4];
        }
        __syncthreads();
        #pragma unroll
        for (int k = 0; k < 32; k += 4) {
            const int kg = kq * 32 + k;
            float a0[4], a1[4], a2[4], a3[4];
            *(float4*)a0 = *(const float4*)&sA[(rowgrp * 4 + 0) * 132 + kg];
            *(float4*)a1 = *(const float4*)&sA[(rowgrp * 4 + 1) * 132 + kg];
            *(float4*)a2 = *(const float4*)&sA[(rowgrp * 4 + 2) * 132 + kg];
            *(float4*)a3 = *(const float4*)&sA[(rowgrp * 4 + 3) * 132 + kg];
            #pragma unroll
            for (int dk = 0; dk < 4; ++dk) {
                float w[8];
                *(float4*)&w[0] = *(const float4*)&sW[(k + dk) * 128 + c0];
                *(float4*)&w[4] = *(const float4*)&sW[(k + dk) * 128 + c0 + 4];
                #pragma unroll
                for (int j = 0; j < 8; ++j) {
                    acc[0][j] = fmaf(a0[dk], w[j], acc[0][j]);
                    acc[1][j] = fmaf(a1[dk], w[j], acc[1][j]);
                    acc[2][j] = fmaf(a2[dk], w[j], acc[2][j]);
                    acc[3][j] = fmaf(a3[dk], w[j], acc[3][j]);
                }
            }
        }
    }

    #pragma unroll
    for (int r = 0; r < 4; ++r) {
        const int row = rbase + rowgrp * 4 + r;
        if (row < NNODES) {
            *(float4*)&y1[(size_t)row * D + c0]     = *(const float4*)&acc[r][0];
            *(float4*)&y1[(size_t)row * D + c0 + 4] = *(const float4*)&acc[r][4];
        }
    }
}

// y2 = h1 @ W2  (tile 64 rows x 64 cols, 256 thr, 2x8 per thread)
__global__ void gemm_y2_kernel(const float* __restrict__ h1, const float* __restrict__ W2,
                               float* __restrict__ y2) {
    __shared__ float sA[64 * 132];
    __shared__ float sW[64 * 64];
    const int tid = threadIdx.x;
    const int rbase = blockIdx.x * 64;
    const int colgrp = tid & 7;
    const int rowgrp = tid >> 3;
    const int c0 = colgrp * 8;

    #pragma unroll
    for (int i = 0; i < 8; ++i) {
        const int f = tid + i * 256;
        const int row = f >> 5, c4 = f & 31;
        int rg = rbase + row;
        if (rg > NNODES - 1) rg = NNODES - 1;
        *(float4*)&sA[row * 132 + c4 * 4] = *(const float4*)&h1[(size_t)rg * D + c4 * 4];
    }

    float acc[2][8];
    #pragma unroll
    for (int r = 0; r < 2; ++r)
        #pragma unroll
        for (int j = 0; j < 8; ++j) acc[r][j] = 0.0f;

    for (int kh = 0; kh < 2; ++kh) {
        __syncthreads();
        #pragma unroll
        for (int i = 0; i < 4; ++i) {
            const int f = tid + i * 256;
            const int kr = f >> 4, c4 = f & 15;
            *(float4*)&sW[kr * 64 + c4 * 4] =
                *(const float4*)&W2[(kh * 64 + kr) * DOUT + c4 * 4];
        }
        __syncthreads();
        #pragma unroll
        for (int k = 0; k < 64; k += 4) {
            const int kg = kh * 64 + k;
            float a0[4], a1[4];
            *(float4*)a0 = *(const float4*)&sA[(rowgrp * 2 + 0) * 132 + kg];
            *(float4*)a1 = *(const float4*)&sA[(rowgrp * 2 + 1) * 132 + kg];
            #pragma unroll
            for (int dk = 0; dk < 4; ++dk) {
                float w[8];
                *(float4*)&w[0] = *(const float4*)&sW[(k + dk) * 64 + c0];
                *(float4*)&w[4] = *(const float4*)&sW[(k + dk) * 64 + c0 + 4];
                #pragma unroll
                for (int j = 0; j < 8; ++j) {
                    acc[0][j] = fmaf(a0[dk], w[j], acc[0][j]);
                    acc[1][j] = fmaf(a1[dk], w[j], acc[1][j]);
                }
            }
        }
    }

    #pragma unroll
    for (int r = 0; r < 2; ++r) {
        const int row = rbase + rowgrp * 2 + r;
        if (row < NNODES) {
            *(float4*)&y2[(size_t)row * DOUT + c0]     = *(const float4*)&acc[r][0];
            *(float4*)&y2[(size_t)row * DOUT + c0 + 4] = *(const float4*)&acc[r][4];
        }
    }
}

// ---------------------------------------------------------------------------
// h1 = relu(mean_agg(y1) + ba): 32 lanes/node, one float4 per lane
__global__ void gather1_kernel(const float4* __restrict__ y1, const int* __restrict__ rowstart,
                               const int* __restrict__ deg, const int* __restrict__ ebuf,
                               const float* __restrict__ ba, float4* __restrict__ h1) {
    const int gid = blockIdx.x * blockDim.x + threadIdx.x;
    const int node = gid >> 5;
    const int sub = gid & 31;
    if (node >= NNODES) return;
    const int beg = rowstart[node];
    const int cnt = deg[node];
    const float4 self = y1[(size_t)node * 32 + sub];
    float ax = self.x, ay = self.y, az = self.z, aw = self.w;
    const int* nb = ebuf + beg;
    int k = 0;
    for (; k + 4 <= cnt; k += 4) {
        const int s0 = nb[k], s1 = nb[k + 1], s2 = nb[k + 2], s3 = nb[k + 3];
        const float4 v0 = y1[(size_t)s0 * 32 + sub];
        const float4 v1 = y1[(size_t)s1 * 32 + sub];
        const float4 v2 = y1[(size_t)s2 * 32 + sub];
        const float4 v3 = y1[(size_t)s3 * 32 + sub];
        ax += (v0.x + v1.x) + (v2.x + v3.x);
        ay += (v0.y + v1.y) + (v2.y + v3.y);
        az += (v0.z + v1.z) + (v2.z + v3.z);
        aw += (v0.w + v1.w) + (v2.w + v3.w);
    }
    for (; k < cnt; ++k) {
        const float4 v = y1[(size_t)nb[k] * 32 + sub];
        ax += v.x; ay += v.y; az += v.z; aw += v.w;
    }
    const float inv = 1.0f / (float)(cnt + 1);
    const float4 bb = ((const float4*)ba)[sub];
    float4 o;
    o.x = fmaxf(fmaf(ax, inv, bb.x), 0.0f);
    o.y = fmaxf(fmaf(ay, inv, bb.y), 0.0f);
    o.z = fmaxf(fmaf(az, inv, bb.z), 0.0f);
    o.w = fmaxf(fmaf(aw, inv, bb.w), 0.0f);
    h1[(size_t)node * 32 + sub] = o;
}

// out = rownorm(mean_agg(y2) + b2): 16 lanes/node, one float4 per lane
__global__ void gather2_kernel(const float4* __restrict__ y2, const int* __restrict__ rowstart,
                               const int* __restrict__ deg, const int* __restrict__ ebuf,
                               const float* __restrict__ b2, float4* __restrict__ out) {
    const int gid = blockIdx.x * blockDim.x + threadIdx.x;
    const int node = gid >> 4;
    const int sub = gid & 15;
    if (node >= NNODES) return;
    const int beg = rowstart[node];
    const int cnt = deg[node];
    const float4 self = y2[(size_t)node * 16 + sub];
    float ax = self.x, ay = self.y, az = self.z, aw = self.w;
    const int* nb = ebuf + beg;
    int k = 0;
    for (; k + 4 <= cnt; k += 4) {
        const int s0 = nb[k], s1 = nb[k + 1], s2 = nb[k + 2], s3 = nb[k + 3];
        const float4 v0 = y2[(size_t)s0 * 16 + sub];
        const float4 v1 = y2[(size_t)s1 * 16 + sub];
        const float4 v2 = y2[(size_t)s2 * 16 + sub];
        const float4 v3 = y2[(size_t)s3 * 16 + sub];
        ax += (v0.x + v1.x) + (v2.x + v3.x);
        ay += (v0.y + v1.y) + (v2.y + v3.y);
        az += (v0.z + v1.z) + (v2.z + v3.z);
        aw += (v0.w + v1.w) + (v2.w + v3.w);
    }
    for (; k < cnt; ++k) {
        const float4 v = y2[(size_t)nb[k] * 16 + sub];
        ax += v.x; ay += v.y; az += v.z; aw += v.w;
    }
    const float inv = 1.0f / (float)(cnt + 1);
    const float4 bb = ((const float4*)b2)[sub];
    float4 v;
    v.x = fmaf(ax, inv, bb.x);
    v.y = fmaf(ay, inv, bb.y);
    v.z = fmaf(az, inv, bb.z);
    v.w = fmaf(aw, inv, bb.w);
    float ss = fmaf(v.x, v.x, fmaf(v.y, v.y, fmaf(v.z, v.z, v.w * v.w)));
    ss += __shfl_xor(ss, 1);
    ss += __shfl_xor(ss, 2);
    ss += __shfl_xor(ss, 4);
    ss += __shfl_xor(ss, 8);
    const float scale = 1.0f / fmaxf(sqrtf(ss), 1e-12f);
    float4 o;
    o.x = v.x * scale; o.y = v.y * scale; o.z = v.z * scale; o.w = v.w * scale;
    out[(size_t)node * 16 + sub] = o;
}

// ---------------------------------------------------------------------------
extern "C" void kernel_launch(void* const* d_in, const int* in_sizes, int n_in,
                              void* d_out, int out_size, void* d_ws, size_t ws_size,
                              hipStream_t stream) {
    const float* x    = (const float*)d_in[0];
    const int*   ei   = (const int*)d_in[1];
    const float* Wpre = (const float*)d_in[2];
    const float* bpre = (const float*)d_in[3];
    const float* W1   = (const float*)d_in[4];
    const float* b1   = (const float*)d_in[5];
    const float* W2   = (const float*)d_in[6];
    const float* b2   = (const float*)d_in[7];
    float* out = (float*)d_out;

    // workspace layout (~55.1 MB)
    char* ws = (char*)d_ws;
    float* bufA     = (float*)ws;                       // y1 [N*128] then y2 [N*64]
    float* h1       = (float*)(ws + 25600000);          // [N*128]
    int*   deg      = (int*)(ws + 51200000);            // [N]
    int*   rowstart = (int*)(ws + 51404800);            // [N]
    int*   cursor   = (int*)(ws + 51609600);            // [N]
    int*   ebuf     = (int*)(ws + 51814400);            // [E]
    float* Wa       = (float*)(ws + 55014400);          // [128*128]
    float* ba       = (float*)(ws + 55079936);          // [128]

    hipMemsetAsync(deg, 0, (size_t)NNODES * sizeof(int), stream);

    // CSR build
    deg_kernel<<<(NEDGES + 255) / 256, 256, 0, stream>>>(ei + NEDGES, deg);
    scan_kernel<<<1, 1024, 0, stream>>>(deg, rowstart, cursor);
    fill_kernel<<<(NEDGES + 255) / 256, 256, 0, stream>>>(ei, cursor, ebuf);

    // folded weights
    combine_w_kernel<<<D + 1, D, 0, stream>>>(Wpre, bpre, W1, b1, Wa, ba);

    // layer 1: y1 = x @ Wa; h1 = relu(mean_agg(y1) + ba)
    gemm_y1_kernel<<<(NNODES + 63) / 64, 256, 0, stream>>>(x, Wa, bufA);
    gather1_kernel<<<(NNODES * 32 + 255) / 256, 256, 0, stream>>>(
        (const float4*)bufA, rowstart, deg, ebuf, ba, (float4*)h1);

    // layer 2: y2 = h1 @ W2; out = rownorm(mean_agg(y2) + b2)
    gemm_y2_kernel<<<(NNODES + 63) / 64, 256, 0, stream>>>(h1, W2, bufA);
    gather2_kernel<<<(NNODES * 16 + 255) / 256, 256, 0, stream>>>(
        (const float4*)bufA, rowstart, deg, ebuf, b2, (float4*)out);
}

// Round 5
// 271.204 us; speedup vs baseline: 10.6049x; 1.6102x over previous
//
#include <hip/hip_runtime.h>
#include <hip/hip_bf16.h>

#define NNODES 50000
#define NEDGES 800000
#define D 128
#define DOUT 64
#define SCAN_BLOCKS 196   // 196*256 = 50176 >= NNODES

typedef unsigned short ushort8 __attribute__((ext_vector_type(8)));

__device__ inline unsigned short f32_to_bf16(float f) {
    unsigned u = __float_as_uint(f);
    u = (u + 0x7fffu + ((u >> 16) & 1u)) >> 16;   // round-to-nearest-even
    return (unsigned short)u;
}

// ---------------------------------------------------------------------------
// deg[i] = in-degree of node i (self-loop handled separately as +1)
__global__ void deg_kernel(const int* __restrict__ dst, int* __restrict__ deg) {
    int i = blockIdx.x * blockDim.x + threadIdx.x;
    if (i < NEDGES) atomicAdd(&deg[dst[i]], 1);
}

// Wa = Wpre @ W1 (128x128), ba = bpre @ W1 + b1 (128)
__global__ void combine_w_kernel(const float* __restrict__ Wpre, const float* __restrict__ bpre,
                                 const float* __restrict__ W1, const float* __restrict__ b1,
                                 float* __restrict__ Wa, float* __restrict__ ba) {
    const int j = threadIdx.x;
    const int i = blockIdx.x;
    if (i < D) {
        float s = 0.0f;
        for (int k = 0; k < D; ++k) s = fmaf(Wpre[i * D + k], W1[k * D + j], s);
        Wa[i * D + j] = s;
    } else {
        float s = b1[j];
        for (int k = 0; k < D; ++k) s = fmaf(bpre[k], W1[k * D + j], s);
        ba[j] = s;
    }
}

// --- hierarchical exclusive scan of deg -> rowstart/cursor -----------------
// P1: per-block (256-elem) inclusive scan; write local exclusive + block total
__global__ void scan_part1(const int* __restrict__ deg, int* __restrict__ excl,
                           int* __restrict__ partials) {
    __shared__ int sm[256];
    const int t = threadIdx.x;
    const int i = blockIdx.x * 256 + t;
    const int v = (i < NNODES) ? deg[i] : 0;
    sm[t] = v;
    __syncthreads();
    #pragma unroll
    for (int off = 1; off < 256; off <<= 1) {
        const int cur = sm[t];
        const int add = (t >= off) ? sm[t - off] : 0;
        __syncthreads();
        sm[t] = cur + add;
        __syncthreads();
    }
    excl[i] = sm[t] - v;                        // excl sized SCAN_BLOCKS*256
    if (t == 255) partials[blockIdx.x] = sm[255];
}

// P2: single block scans the block totals -> exclusive block bases
__global__ void scan_part2(const int* __restrict__ partials, int* __restrict__ blockbase) {
    __shared__ int sm[256];
    const int t = threadIdx.x;
    const int v = (t < SCAN_BLOCKS) ? partials[t] : 0;
    sm[t] = v;
    __syncthreads();
    #pragma unroll
    for (int off = 1; off < 256; off <<= 1) {
        const int cur = sm[t];
        const int add = (t >= off) ? sm[t - off] : 0;
        __syncthreads();
        sm[t] = cur + add;
        __syncthreads();
    }
    blockbase[t] = sm[t] - v;
}

// P3: rowstart[i] = blockbase[b] + excl[i]; cursor likewise
__global__ void scan_part3(const int* __restrict__ excl, const int* __restrict__ blockbase,
                           int* __restrict__ rowstart, int* __restrict__ cursor) {
    const int i = blockIdx.x * 256 + threadIdx.x;
    if (i < NNODES) {
        const int val = blockbase[blockIdx.x] + excl[i];
        rowstart[i] = val;
        cursor[i] = val;
    }
}

// bucket-fill CSR: ebuf[rowstart[dst]..] = src ids
__global__ void fill_kernel(const int* __restrict__ ei, int* __restrict__ cursor,
                            int* __restrict__ ebuf) {
    int e = blockIdx.x * blockDim.x + threadIdx.x;
    if (e < NEDGES) {
        const int d = ei[NEDGES + e];
        const int pos = atomicAdd(&cursor[d], 1);
        ebuf[pos] = ei[e];
    }
}

// ---------------------------------------------------------------------------
// y1 = bf16(x @ Wa)   (tile 64 rows x 128 cols, 256 thr, 4x8 per thread)
__global__ void gemm_y1_kernel(const float* __restrict__ x, const float* __restrict__ Wa,
                               unsigned short* __restrict__ y1) {
    __shared__ float sA[64 * 132];
    __shared__ float sW[32 * 128];
    const int tid = threadIdx.x;
    const int rbase = blockIdx.x * 64;
    const int colgrp = tid & 15;
    const int rowgrp = tid >> 4;
    const int c0 = colgrp * 8;

    #pragma unroll
    for (int i = 0; i < 8; ++i) {
        const int f = tid + i * 256;
        const int row = f >> 5, c4 = f & 31;
        int rg = rbase + row;
        if (rg > NNODES - 1) rg = NNODES - 1;
        *(float4*)&sA[row * 132 + c4 * 4] = *(const float4*)&x[(size_t)rg * D + c4 * 4];
    }

    float acc[4][8];
    #pragma unroll
    for (int r = 0; r < 4; ++r)
        #pragma unroll
        for (int j = 0; j < 8; ++j) acc[r][j] = 0.0f;

    for (int kq = 0; kq < 4; ++kq) {
        __syncthreads();
        #pragma unroll
        for (int i = 0; i < 4; ++i) {
            const int f = tid + i * 256;
            const int kr = f >> 5, c4 = f & 31;
            *(float4*)&sW[kr * 128 + c4 * 4] =
                *(const float4*)&Wa[(kq * 32 + kr) * D + c4 * 4];
        }
        __syncthreads();
        #pragma unroll
        for (int k = 0; k < 32; k += 4) {
            const int kg = kq * 32 + k;
            float a0[4], a1[4], a2[4], a3[4];
            *(float4*)a0 = *(const float4*)&sA[(rowgrp * 4 + 0) * 132 + kg];
            *(float4*)a1 = *(const float4*)&sA[(rowgrp * 4 + 1) * 132 + kg];
            *(float4*)a2 = *(const float4*)&sA[(rowgrp * 4 + 2) * 132 + kg];
            *(float4*)a3 = *(const float4*)&sA[(rowgrp * 4 + 3) * 132 + kg];
            #pragma unroll
            for (int dk = 0; dk < 4; ++dk) {
                float w[8];
                *(float4*)&w[0] = *(const float4*)&sW[(k + dk) * 128 + c0];
                *(float4*)&w[4] = *(const float4*)&sW[(k + dk) * 128 + c0 + 4];
                #pragma unroll
                for (int j = 0; j < 8; ++j) {
                    acc[0][j] = fmaf(a0[dk], w[j], acc[0][j]);
                    acc[1][j] = fmaf(a1[dk], w[j], acc[1][j]);
                    acc[2][j] = fmaf(a2[dk], w[j], acc[2][j]);
                    acc[3][j] = fmaf(a3[dk], w[j], acc[3][j]);
                }
            }
        }
    }

    #pragma unroll
    for (int r = 0; r < 4; ++r) {
        const int row = rbase + rowgrp * 4 + r;
        if (row < NNODES) {
            ushort8 o;
            #pragma unroll
            for (int j = 0; j < 8; ++j) o[j] = f32_to_bf16(acc[r][j]);
            *(ushort8*)&y1[(size_t)row * D + c0] = o;
        }
    }
}

// y2 = bf16(h1 @ W2)  (tile 64 rows x 64 cols, 256 thr, 2x8 per thread)
__global__ void gemm_y2_kernel(const float* __restrict__ h1, const float* __restrict__ W2,
                               unsigned short* __restrict__ y2) {
    __shared__ float sA[64 * 132];
    __shared__ float sW[64 * 64];
    const int tid = threadIdx.x;
    const int rbase = blockIdx.x * 64;
    const int colgrp = tid & 7;
    const int rowgrp = tid >> 3;
    const int c0 = colgrp * 8;

    #pragma unroll
    for (int i = 0; i < 8; ++i) {
        const int f = tid + i * 256;
        const int row = f >> 5, c4 = f & 31;
        int rg = rbase + row;
        if (rg > NNODES - 1) rg = NNODES - 1;
        *(float4*)&sA[row * 132 + c4 * 4] = *(const float4*)&h1[(size_t)rg * D + c4 * 4];
    }

    float acc[2][8];
    #pragma unroll
    for (int r = 0; r < 2; ++r)
        #pragma unroll
        for (int j = 0; j < 8; ++j) acc[r][j] = 0.0f;

    for (int kh = 0; kh < 2; ++kh) {
        __syncthreads();
        #pragma unroll
        for (int i = 0; i < 4; ++i) {
            const int f = tid + i * 256;
            const int kr = f >> 4, c4 = f & 15;
            *(float4*)&sW[kr * 64 + c4 * 4] =
                *(const float4*)&W2[(kh * 64 + kr) * DOUT + c4 * 4];
        }
        __syncthreads();
        #pragma unroll
        for (int k = 0; k < 64; k += 4) {
            const int kg = kh * 64 + k;
            float a0[4], a1[4];
            *(float4*)a0 = *(const float4*)&sA[(rowgrp * 2 + 0) * 132 + kg];
            *(float4*)a1 = *(const float4*)&sA[(rowgrp * 2 + 1) * 132 + kg];
            #pragma unroll
            for (int dk = 0; dk < 4; ++dk) {
                float w[8];
                *(float4*)&w[0] = *(const float4*)&sW[(k + dk) * 64 + c0];
                *(float4*)&w[4] = *(const float4*)&sW[(k + dk) * 64 + c0 + 4];
                #pragma unroll
                for (int j = 0; j < 8; ++j) {
                    acc[0][j] = fmaf(a0[dk], w[j], acc[0][j]);
                    acc[1][j] = fmaf(a1[dk], w[j], acc[1][j]);
                }
            }
        }
    }

    #pragma unroll
    for (int r = 0; r < 2; ++r) {
        const int row = rbase + rowgrp * 2 + r;
        if (row < NNODES) {
            ushort8 o;
            #pragma unroll
            for (int j = 0; j < 8; ++j) o[j] = f32_to_bf16(acc[r][j]);
            *(ushort8*)&y2[(size_t)row * DOUT + c0] = o;
        }
    }
}

// ---------------------------------------------------------------------------
#define ACC8(q)                                                        \
    do {                                                               \
        a[0] += __uint_as_float((q).x << 16);                          \
        a[1] += __uint_as_float((q).x & 0xffff0000u);                  \
        a[2] += __uint_as_float((q).y << 16);                          \
        a[3] += __uint_as_float((q).y & 0xffff0000u);                  \
        a[4] += __uint_as_float((q).z << 16);                          \
        a[5] += __uint_as_float((q).z & 0xffff0000u);                  \
        a[6] += __uint_as_float((q).w << 16);                          \
        a[7] += __uint_as_float((q).w & 0xffff0000u);                  \
    } while (0)

// h1 = relu(mean_agg(y1) + ba): 16 lanes/node, one uint4 (8 bf16) per lane
__global__ void gather1_kernel(const uint4* __restrict__ y1, const int* __restrict__ rowstart,
                               const int* __restrict__ deg, const int* __restrict__ ebuf,
                               const float* __restrict__ ba, float* __restrict__ h1) {
    const int gid = blockIdx.x * blockDim.x + threadIdx.x;
    const int node = gid >> 4;
    const int sub = gid & 15;
    if (node >= NNODES) return;
    const int beg = rowstart[node];
    const int cnt = deg[node];
    float a[8];
    {
        const uint4 q = y1[(size_t)node * 16 + sub];
        a[0] = __uint_as_float(q.x << 16);  a[1] = __uint_as_float(q.x & 0xffff0000u);
        a[2] = __uint_as_float(q.y << 16);  a[3] = __uint_as_float(q.y & 0xffff0000u);
        a[4] = __uint_as_float(q.z << 16);  a[5] = __uint_as_float(q.z & 0xffff0000u);
        a[6] = __uint_as_float(q.w << 16);  a[7] = __uint_as_float(q.w & 0xffff0000u);
    }
    const int* nb = ebuf + beg;
    int k = 0;
    for (; k + 4 <= cnt; k += 4) {
        const int s0 = nb[k], s1 = nb[k + 1], s2 = nb[k + 2], s3 = nb[k + 3];
        const uint4 q0 = y1[(size_t)s0 * 16 + sub];
        const uint4 q1 = y1[(size_t)s1 * 16 + sub];
        const uint4 q2 = y1[(size_t)s2 * 16 + sub];
        const uint4 q3 = y1[(size_t)s3 * 16 + sub];
        ACC8(q0); ACC8(q1); ACC8(q2); ACC8(q3);
    }
    for (; k < cnt; ++k) {
        const uint4 q = y1[(size_t)nb[k] * 16 + sub];
        ACC8(q);
    }
    const float inv = 1.0f / (float)(cnt + 1);
    float o[8];
    #pragma unroll
    for (int j = 0; j < 8; ++j)
        o[j] = fmaxf(fmaf(a[j], inv, ba[sub * 8 + j]), 0.0f);
    float* dst = &h1[(size_t)node * D + sub * 8];
    *(float4*)&dst[0] = *(const float4*)&o[0];
    *(float4*)&dst[4] = *(const float4*)&o[4];
}

// out = rownorm(mean_agg(y2) + b2): 8 lanes/node, one uint4 (8 bf16) per lane
__global__ void gather2_kernel(const uint4* __restrict__ y2, const int* __restrict__ rowstart,
                               const int* __restrict__ deg, const int* __restrict__ ebuf,
                               const float* __restrict__ b2, float* __restrict__ out) {
    const int gid = blockIdx.x * blockDim.x + threadIdx.x;
    const int node = gid >> 3;
    const int sub = gid & 7;
    if (node >= NNODES) return;
    const int beg = rowstart[node];
    const int cnt = deg[node];
    float a[8];
    {
        const uint4 q = y2[(size_t)node * 8 + sub];
        a[0] = __uint_as_float(q.x << 16);  a[1] = __uint_as_float(q.x & 0xffff0000u);
        a[2] = __uint_as_float(q.y << 16);  a[3] = __uint_as_float(q.y & 0xffff0000u);
        a[4] = __uint_as_float(q.z << 16);  a[5] = __uint_as_float(q.z & 0xffff0000u);
        a[6] = __uint_as_float(q.w << 16);  a[7] = __uint_as_float(q.w & 0xffff0000u);
    }
    const int* nb = ebuf + beg;
    int k = 0;
    for (; k + 4 <= cnt; k += 4) {
        const int s0 = nb[k], s1 = nb[k + 1], s2 = nb[k + 2], s3 = nb[k + 3];
        const uint4 q0 = y2[(size_t)s0 * 8 + sub];
        const uint4 q1 = y2[(size_t)s1 * 8 + sub];
        const uint4 q2 = y2[(size_t)s2 * 8 + sub];
        const uint4 q3 = y2[(size_t)s3 * 8 + sub];
        ACC8(q0); ACC8(q1); ACC8(q2); ACC8(q3);
    }
    for (; k < cnt; ++k) {
        const uint4 q = y2[(size_t)nb[k] * 8 + sub];
        ACC8(q);
    }
    const float inv = 1.0f / (float)(cnt + 1);
    float v[8];
    float ss = 0.0f;
    #pragma unroll
    for (int j = 0; j < 8; ++j) {
        v[j] = fmaf(a[j], inv, b2[sub * 8 + j]);
        ss = fmaf(v[j], v[j], ss);
    }
    ss += __shfl_xor(ss, 1);
    ss += __shfl_xor(ss, 2);
    ss += __shfl_xor(ss, 4);
    const float scale = 1.0f / fmaxf(sqrtf(ss), 1e-12f);
    float o[8];
    #pragma unroll
    for (int j = 0; j < 8; ++j) o[j] = v[j] * scale;
    float* dst = &out[(size_t)node * DOUT + sub * 8];
    *(float4*)&dst[0] = *(const float4*)&o[0];
    *(float4*)&dst[4] = *(const float4*)&o[4];
}

// ---------------------------------------------------------------------------
extern "C" void kernel_launch(void* const* d_in, const int* in_sizes, int n_in,
                              void* d_out, int out_size, void* d_ws, size_t ws_size,
                              hipStream_t stream) {
    const float* x    = (const float*)d_in[0];
    const int*   ei   = (const int*)d_in[1];
    const float* Wpre = (const float*)d_in[2];
    const float* bpre = (const float*)d_in[3];
    const float* W1   = (const float*)d_in[4];
    const float* b1   = (const float*)d_in[5];
    const float* W2   = (const float*)d_in[6];
    const float* b2   = (const float*)d_in[7];
    float* out = (float*)d_out;

    // workspace layout (~48.9 MB)
    char* ws = (char*)d_ws;
    unsigned short* y1 = (unsigned short*)ws;            // [N*128] bf16 = 12.8 MB
    float* h1          = (float*)(ws + 12800000);        // [N*128] f32  = 25.6 MB
    unsigned short* y2 = (unsigned short*)(ws + 38400000); // [N*64] bf16 = 6.4 MB
    int* deg       = (int*)(ws + 44800000);              // [N]
    int* rowstart  = (int*)(ws + 45000000);              // [N]
    int* cursor    = (int*)(ws + 45200000);              // [N]
    int* ebuf      = (int*)(ws + 45400000);              // [E] = 3.2 MB
    int* excl      = (int*)(ws + 48600000);              // [SCAN_BLOCKS*256]
    int* partials  = (int*)(ws + 48800768);              // [256]
    int* blockbase = (int*)(ws + 48801792);              // [256]
    float* Wa      = (float*)(ws + 48802816);            // [128*128]
    float* ba      = (float*)(ws + 48868352);            // [128]

    hipMemsetAsync(deg, 0, (size_t)NNODES * sizeof(int), stream);

    // CSR build
    deg_kernel<<<(NEDGES + 255) / 256, 256, 0, stream>>>(ei + NEDGES, deg);
    scan_part1<<<SCAN_BLOCKS, 256, 0, stream>>>(deg, excl, partials);
    scan_part2<<<1, 256, 0, stream>>>(partials, blockbase);
    scan_part3<<<SCAN_BLOCKS, 256, 0, stream>>>(excl, blockbase, rowstart, cursor);
    fill_kernel<<<(NEDGES + 255) / 256, 256, 0, stream>>>(ei, cursor, ebuf);

    // folded weights
    combine_w_kernel<<<D + 1, D, 0, stream>>>(Wpre, bpre, W1, b1, Wa, ba);

    // layer 1: y1 = bf16(x @ Wa); h1 = relu(mean_agg(y1) + ba)
    gemm_y1_kernel<<<(NNODES + 63) / 64, 256, 0, stream>>>(x, Wa, y1);
    gather1_kernel<<<(NNODES * 16 + 255) / 256, 256, 0, stream>>>(
        (const uint4*)y1, rowstart, deg, ebuf, ba, h1);

    // layer 2: y2 = bf16(h1 @ W2); out = rownorm(mean_agg(y2) + b2)
    gemm_y2_kernel<<<(NNODES + 63) / 64, 256, 0, stream>>>(h1, W2, y2);
    gather2_kernel<<<(NNODES * 8 + 255) / 256, 256, 0, stream>>>(
        (const uint4*)y2, rowstart, deg, ebuf, b2, out);
}

// Round 6
// 263.732 us; speedup vs baseline: 10.9053x; 1.0283x over previous
//
#include <hip/hip_runtime.h>
#include <hip/hip_bf16.h>

#define NNODES 50000
#define NEDGES 800000
#define D 128
#define DOUT 64
#define SCAN_BLOCKS 196   // 196*256 = 50176 >= NNODES
#define NPB 16            // nodes per block in fused gather1+gemm2

typedef unsigned short ushort8 __attribute__((ext_vector_type(8)));

__device__ inline unsigned short f32_to_bf16(float f) {
    unsigned u = __float_as_uint(f);
    u = (u + 0x7fffu + ((u >> 16) & 1u)) >> 16;   // round-to-nearest-even
    return (unsigned short)u;
}

// ---------------------------------------------------------------------------
// deg[i] = in-degree of node i (self-loop handled separately as +1)
__global__ void deg_kernel(const int* __restrict__ dst, int* __restrict__ deg) {
    int i = blockIdx.x * blockDim.x + threadIdx.x;
    if (i < NEDGES) atomicAdd(&deg[dst[i]], 1);
}

// Wa = Wpre @ W1 (128x128), ba = bpre @ W1 + b1 (128)
__global__ void combine_w_kernel(const float* __restrict__ Wpre, const float* __restrict__ bpre,
                                 const float* __restrict__ W1, const float* __restrict__ b1,
                                 float* __restrict__ Wa, float* __restrict__ ba) {
    const int j = threadIdx.x;
    const int i = blockIdx.x;
    if (i < D) {
        float s = 0.0f;
        for (int k = 0; k < D; ++k) s = fmaf(Wpre[i * D + k], W1[k * D + j], s);
        Wa[i * D + j] = s;
    } else {
        float s = b1[j];
        for (int k = 0; k < D; ++k) s = fmaf(bpre[k], W1[k * D + j], s);
        ba[j] = s;
    }
}

// --- hierarchical exclusive scan of deg -> rowstart/cursor -----------------
__global__ void scan_part1(const int* __restrict__ deg, int* __restrict__ excl,
                           int* __restrict__ partials) {
    __shared__ int sm[256];
    const int t = threadIdx.x;
    const int i = blockIdx.x * 256 + t;
    const int v = (i < NNODES) ? deg[i] : 0;
    sm[t] = v;
    __syncthreads();
    #pragma unroll
    for (int off = 1; off < 256; off <<= 1) {
        const int cur = sm[t];
        const int add = (t >= off) ? sm[t - off] : 0;
        __syncthreads();
        sm[t] = cur + add;
        __syncthreads();
    }
    excl[i] = sm[t] - v;
    if (t == 255) partials[blockIdx.x] = sm[255];
}

__global__ void scan_part2(const int* __restrict__ partials, int* __restrict__ blockbase) {
    __shared__ int sm[256];
    const int t = threadIdx.x;
    const int v = (t < SCAN_BLOCKS) ? partials[t] : 0;
    sm[t] = v;
    __syncthreads();
    #pragma unroll
    for (int off = 1; off < 256; off <<= 1) {
        const int cur = sm[t];
        const int add = (t >= off) ? sm[t - off] : 0;
        __syncthreads();
        sm[t] = cur + add;
        __syncthreads();
    }
    blockbase[t] = sm[t] - v;
}

__global__ void scan_part3(const int* __restrict__ excl, const int* __restrict__ blockbase,
                           int* __restrict__ rowstart, int* __restrict__ cursor) {
    const int i = blockIdx.x * 256 + threadIdx.x;
    if (i < NNODES) {
        const int val = blockbase[blockIdx.x] + excl[i];
        rowstart[i] = val;
        cursor[i] = val;
    }
}

// bucket-fill CSR: ebuf[rowstart[dst]..] = src ids (ushort: src < 65536)
__global__ void fill_kernel(const int* __restrict__ ei, int* __restrict__ cursor,
                            unsigned short* __restrict__ ebuf) {
    int e = blockIdx.x * blockDim.x + threadIdx.x;
    if (e < NEDGES) {
        const int d = ei[NEDGES + e];
        const int pos = atomicAdd(&cursor[d], 1);
        ebuf[pos] = (unsigned short)ei[e];
    }
}

// ---------------------------------------------------------------------------
// y1 = bf16(x @ Wa)   (tile 64 rows x 128 cols, 256 thr, 4x8 per thread)
__global__ void gemm_y1_kernel(const float* __restrict__ x, const float* __restrict__ Wa,
                               unsigned short* __restrict__ y1) {
    __shared__ float sA[64 * 132];
    __shared__ float sW[32 * 128];
    const int tid = threadIdx.x;
    const int rbase = blockIdx.x * 64;
    const int colgrp = tid & 15;
    const int rowgrp = tid >> 4;
    const int c0 = colgrp * 8;

    #pragma unroll
    for (int i = 0; i < 8; ++i) {
        const int f = tid + i * 256;
        const int row = f >> 5, c4 = f & 31;
        int rg = rbase + row;
        if (rg > NNODES - 1) rg = NNODES - 1;
        *(float4*)&sA[row * 132 + c4 * 4] = *(const float4*)&x[(size_t)rg * D + c4 * 4];
    }

    float acc[4][8];
    #pragma unroll
    for (int r = 0; r < 4; ++r)
        #pragma unroll
        for (int j = 0; j < 8; ++j) acc[r][j] = 0.0f;

    for (int kq = 0; kq < 4; ++kq) {
        __syncthreads();
        #pragma unroll
        for (int i = 0; i < 4; ++i) {
            const int f = tid + i * 256;
            const int kr = f >> 5, c4 = f & 31;
            *(float4*)&sW[kr * 128 + c4 * 4] =
                *(const float4*)&Wa[(kq * 32 + kr) * D + c4 * 4];
        }
        __syncthreads();
        #pragma unroll
        for (int k = 0; k < 32; k += 4) {
            const int kg = kq * 32 + k;
            float a0[4], a1[4], a2[4], a3[4];
            *(float4*)a0 = *(const float4*)&sA[(rowgrp * 4 + 0) * 132 + kg];
            *(float4*)a1 = *(const float4*)&sA[(rowgrp * 4 + 1) * 132 + kg];
            *(float4*)a2 = *(const float4*)&sA[(rowgrp * 4 + 2) * 132 + kg];
            *(float4*)a3 = *(const float4*)&sA[(rowgrp * 4 + 3) * 132 + kg];
            #pragma unroll
            for (int dk = 0; dk < 4; ++dk) {
                float w[8];
                *(float4*)&w[0] = *(const float4*)&sW[(k + dk) * 128 + c0];
                *(float4*)&w[4] = *(const float4*)&sW[(k + dk) * 128 + c0 + 4];
                #pragma unroll
                for (int j = 0; j < 8; ++j) {
                    acc[0][j] = fmaf(a0[dk], w[j], acc[0][j]);
                    acc[1][j] = fmaf(a1[dk], w[j], acc[1][j]);
                    acc[2][j] = fmaf(a2[dk], w[j], acc[2][j]);
                    acc[3][j] = fmaf(a3[dk], w[j], acc[3][j]);
                }
            }
        }
    }

    #pragma unroll
    for (int r = 0; r < 4; ++r) {
        const int row = rbase + rowgrp * 4 + r;
        if (row < NNODES) {
            ushort8 o;
            #pragma unroll
            for (int j = 0; j < 8; ++j) o[j] = f32_to_bf16(acc[r][j]);
            *(ushort8*)&y1[(size_t)row * D + c0] = o;
        }
    }
}

// ---------------------------------------------------------------------------
#define ACC8(q)                                                        \
    do {                                                               \
        a[0] += __uint_as_float((q).x << 16);                          \
        a[1] += __uint_as_float((q).x & 0xffff0000u);                  \
        a[2] += __uint_as_float((q).y << 16);                          \
        a[3] += __uint_as_float((q).y & 0xffff0000u);                  \
        a[4] += __uint_as_float((q).z << 16);                          \
        a[5] += __uint_as_float((q).z & 0xffff0000u);                  \
        a[6] += __uint_as_float((q).w << 16);                          \
        a[7] += __uint_as_float((q).w & 0xffff0000u);                  \
    } while (0)

// Fused: h1 = relu(mean_agg(y1)+ba) -> LDS (f32); y2 = bf16(h1 @ W2)
// block = 256 thr = 16 nodes x 16 lanes; NNODES = 3125 * NPB exactly
__global__ void gather1_gemm2_kernel(const uint4* __restrict__ y1,
                                     const int* __restrict__ rowstart,
                                     const int* __restrict__ deg,
                                     const unsigned short* __restrict__ ebuf,
                                     const float* __restrict__ ba,
                                     const float* __restrict__ W2,
                                     unsigned short* __restrict__ y2) {
    __shared__ float h1s[NPB][132];   // stride 132: 16B-aligned rows, conflict-free
    __shared__ float w2s[32][132];    // transposed col-half of W2: w2s[c][k]
    const int tid = threadIdx.x;
    const int nloc = tid >> 4;        // 0..15
    const int sub = tid & 15;         // 0..15
    const int node = blockIdx.x * NPB + nloc;

    // ---- phase 1: gather + mean + bias + relu -> h1s (f32) ----
    const int beg = rowstart[node];
    const int cnt = deg[node];
    float a[8];
    {
        const uint4 q = y1[(size_t)node * 16 + sub];   // self loop
        a[0] = __uint_as_float(q.x << 16);  a[1] = __uint_as_float(q.x & 0xffff0000u);
        a[2] = __uint_as_float(q.y << 16);  a[3] = __uint_as_float(q.y & 0xffff0000u);
        a[4] = __uint_as_float(q.z << 16);  a[5] = __uint_as_float(q.z & 0xffff0000u);
        a[6] = __uint_as_float(q.w << 16);  a[7] = __uint_as_float(q.w & 0xffff0000u);
    }
    const unsigned short* nb = ebuf + beg;
    int k = 0;
    for (; k + 4 <= cnt; k += 4) {
        const int s0 = nb[k], s1 = nb[k + 1], s2 = nb[k + 2], s3 = nb[k + 3];
        const uint4 q0 = y1[(size_t)s0 * 16 + sub];
        const uint4 q1 = y1[(size_t)s1 * 16 + sub];
        const uint4 q2 = y1[(size_t)s2 * 16 + sub];
        const uint4 q3 = y1[(size_t)s3 * 16 + sub];
        ACC8(q0); ACC8(q1); ACC8(q2); ACC8(q3);
    }
    for (; k < cnt; ++k) {
        const uint4 q = y1[(size_t)nb[k] * 16 + sub];
        ACC8(q);
    }
    const float inv = 1.0f / (float)(cnt + 1);
    #pragma unroll
    for (int j = 0; j < 8; ++j)
        h1s[nloc][sub * 8 + j] = fmaxf(fmaf(a[j], inv, ba[sub * 8 + j]), 0.0f);

    // ---- phase 2: y2 = h1 @ W2 in two 32-col halves ----
    for (int kh = 0; kh < 2; ++kh) {
        __syncthreads();              // h1s ready / previous half consumed
        #pragma unroll
        for (int i = 0; i < 4; ++i) {
            const int f = tid + i * 256;      // 1024 float4 slots = 128 rows x 8
            const int kk = f >> 3;            // 0..127
            const int c4 = f & 7;             // 0..7
            const float4 w = *(const float4*)&W2[kk * DOUT + kh * 32 + c4 * 4];
            w2s[c4 * 4 + 0][kk] = w.x;
            w2s[c4 * 4 + 1][kk] = w.y;
            w2s[c4 * 4 + 2][kk] = w.z;
            w2s[c4 * 4 + 3][kk] = w.w;
        }
        __syncthreads();
        float acc0 = 0.0f, acc1 = 0.0f;
        #pragma unroll
        for (int kk = 0; kk < D; kk += 4) {
            const float4 hv = *(const float4*)&h1s[nloc][kk];
            const float4 w0 = *(const float4*)&w2s[sub][kk];
            const float4 w1 = *(const float4*)&w2s[sub + 16][kk];
            acc0 = fmaf(hv.x, w0.x, fmaf(hv.y, w0.y, fmaf(hv.z, w0.z, fmaf(hv.w, w0.w, acc0))));
            acc1 = fmaf(hv.x, w1.x, fmaf(hv.y, w1.y, fmaf(hv.z, w1.z, fmaf(hv.w, w1.w, acc1))));
        }
        y2[(size_t)node * DOUT + kh * 32 + sub]      = f32_to_bf16(acc0);
        y2[(size_t)node * DOUT + kh * 32 + sub + 16] = f32_to_bf16(acc1);
    }
}

// out = rownorm(mean_agg(y2) + b2): 8 lanes/node, one uint4 (8 bf16) per lane
__global__ void gather2_kernel(const uint4* __restrict__ y2, const int* __restrict__ rowstart,
                               const int* __restrict__ deg, const unsigned short* __restrict__ ebuf,
                               const float* __restrict__ b2, float* __restrict__ out) {
    const int gid = blockIdx.x * blockDim.x + threadIdx.x;
    const int node = gid >> 3;
    const int sub = gid & 7;
    if (node >= NNODES) return;
    const int beg = rowstart[node];
    const int cnt = deg[node];
    float a[8];
    {
        const uint4 q = y2[(size_t)node * 8 + sub];
        a[0] = __uint_as_float(q.x << 16);  a[1] = __uint_as_float(q.x & 0xffff0000u);
        a[2] = __uint_as_float(q.y << 16);  a[3] = __uint_as_float(q.y & 0xffff0000u);
        a[4] = __uint_as_float(q.z << 16);  a[5] = __uint_as_float(q.z & 0xffff0000u);
        a[6] = __uint_as_float(q.w << 16);  a[7] = __uint_as_float(q.w & 0xffff0000u);
    }
    const unsigned short* nb = ebuf + beg;
    int k = 0;
    for (; k + 4 <= cnt; k += 4) {
        const int s0 = nb[k], s1 = nb[k + 1], s2 = nb[k + 2], s3 = nb[k + 3];
        const uint4 q0 = y2[(size_t)s0 * 8 + sub];
        const uint4 q1 = y2[(size_t)s1 * 8 + sub];
        const uint4 q2 = y2[(size_t)s2 * 8 + sub];
        const uint4 q3 = y2[(size_t)s3 * 8 + sub];
        ACC8(q0); ACC8(q1); ACC8(q2); ACC8(q3);
    }
    for (; k < cnt; ++k) {
        const uint4 q = y2[(size_t)nb[k] * 8 + sub];
        ACC8(q);
    }
    const float inv = 1.0f / (float)(cnt + 1);
    float v[8];
    float ss = 0.0f;
    #pragma unroll
    for (int j = 0; j < 8; ++j) {
        v[j] = fmaf(a[j], inv, b2[sub * 8 + j]);
        ss = fmaf(v[j], v[j], ss);
    }
    ss += __shfl_xor(ss, 1);
    ss += __shfl_xor(ss, 2);
    ss += __shfl_xor(ss, 4);
    const float scale = 1.0f / fmaxf(sqrtf(ss), 1e-12f);
    float o[8];
    #pragma unroll
    for (int j = 0; j < 8; ++j) o[j] = v[j] * scale;
    float* dst = &out[(size_t)node * DOUT + sub * 8];
    *(float4*)&dst[0] = *(const float4*)&o[0];
    *(float4*)&dst[4] = *(const float4*)&o[4];
}

// ---------------------------------------------------------------------------
extern "C" void kernel_launch(void* const* d_in, const int* in_sizes, int n_in,
                              void* d_out, int out_size, void* d_ws, size_t ws_size,
                              hipStream_t stream) {
    const float* x    = (const float*)d_in[0];
    const int*   ei   = (const int*)d_in[1];
    const float* Wpre = (const float*)d_in[2];
    const float* bpre = (const float*)d_in[3];
    const float* W1   = (const float*)d_in[4];
    const float* b1   = (const float*)d_in[5];
    const float* W2   = (const float*)d_in[6];
    const float* b2   = (const float*)d_in[7];
    float* out = (float*)d_out;

    // workspace layout (~21.7 MB)
    char* ws = (char*)d_ws;
    unsigned short* y1   = (unsigned short*)ws;                 // [N*128] bf16 = 12.8 MB
    unsigned short* y2   = (unsigned short*)(ws + 12800000);    // [N*64]  bf16 = 6.4 MB
    int* deg             = (int*)(ws + 19200000);               // [N]
    int* rowstart        = (int*)(ws + 19400000);               // [N]
    int* cursor          = (int*)(ws + 19600000);               // [N]
    unsigned short* ebuf = (unsigned short*)(ws + 19800000);    // [E] ushort = 1.6 MB
    int* excl            = (int*)(ws + 21400000);               // [SCAN_BLOCKS*256]
    int* partials        = (int*)(ws + 21600704);               // [256]
    int* blockbase       = (int*)(ws + 21601728);               // [256]
    float* Wa            = (float*)(ws + 21602752);             // [128*128]
    float* ba            = (float*)(ws + 21668288);             // [128]

    hipMemsetAsync(deg, 0, (size_t)NNODES * sizeof(int), stream);

    // CSR build
    deg_kernel<<<(NEDGES + 255) / 256, 256, 0, stream>>>(ei + NEDGES, deg);
    scan_part1<<<SCAN_BLOCKS, 256, 0, stream>>>(deg, excl, partials);
    scan_part2<<<1, 256, 0, stream>>>(partials, blockbase);
    scan_part3<<<SCAN_BLOCKS, 256, 0, stream>>>(excl, blockbase, rowstart, cursor);
    fill_kernel<<<(NEDGES + 255) / 256, 256, 0, stream>>>(ei, cursor, ebuf);

    // folded weights
    combine_w_kernel<<<D + 1, D, 0, stream>>>(Wpre, bpre, W1, b1, Wa, ba);

    // layer 1: y1 = bf16(x @ Wa)
    gemm_y1_kernel<<<(NNODES + 63) / 64, 256, 0, stream>>>(x, Wa, y1);

    // fused: h1 = relu(mean_agg(y1)+ba) in LDS; y2 = bf16(h1 @ W2)
    gather1_gemm2_kernel<<<NNODES / NPB, 256, 0, stream>>>(
        (const uint4*)y1, rowstart, deg, ebuf, ba, W2, y2);

    // layer 2 aggregate + normalize
    gather2_kernel<<<(NNODES * 8 + 255) / 256, 256, 0, stream>>>(
        (const uint4*)y2, rowstart, deg, ebuf, b2, out);
}

// Round 7
// 216.061 us; speedup vs baseline: 13.3114x; 1.2206x over previous
//
#include <hip/hip_runtime.h>
#include <hip/hip_bf16.h>

#define NNODES 50000
#define NEDGES 800000
#define D 128
#define DOUT 64
#define SCAN_BLOCKS 196   // 196*256 = 50176 >= NNODES
#define NPB 16            // nodes per block in fused gather1+gemm2

// binned CSR build
#define BSHIFT 7
#define BMASK 127
#define NBUCK 391         // ceil(50000/128)
#define BCAP 2560         // bucket capacity (mean 2048, sigma~45 -> >11 sigma)
#define CH 2048           // edges per bin block

typedef unsigned short ushort8 __attribute__((ext_vector_type(8)));

__device__ inline unsigned short f32_to_bf16(float f) {
    unsigned u = __float_as_uint(f);
    u = (u + 0x7fffu + ((u >> 16) & 1u)) >> 16;   // round-to-nearest-even
    return (unsigned short)u;
}

// ---------------------------------------------------------------------------
// Wa = Wpre @ W1 (128x128), ba = bpre @ W1 + b1 (128)
__global__ void combine_w_kernel(const float* __restrict__ Wpre, const float* __restrict__ bpre,
                                 const float* __restrict__ W1, const float* __restrict__ b1,
                                 float* __restrict__ Wa, float* __restrict__ ba) {
    const int j = threadIdx.x;
    const int i = blockIdx.x;
    if (i < D) {
        float s = 0.0f;
        for (int k = 0; k < D; ++k) s = fmaf(Wpre[i * D + k], W1[k * D + j], s);
        Wa[i * D + j] = s;
    } else {
        float s = b1[j];
        for (int k = 0; k < D; ++k) s = fmaf(bpre[k], W1[k * D + j], s);
        ba[j] = s;
    }
}

// --- binned CSR build ------------------------------------------------------
__global__ void binit_kernel(int* __restrict__ bcursor) {
    const int b = blockIdx.x * 256 + threadIdx.x;
    if (b < NBUCK) bcursor[b] = b * BCAP;
}

// bin edges by dst>>7 into fixed-capacity bucket regions.
// Block-level: LDS count -> one global atomicAdd per bucket -> dense runs.
__global__ void bin_kernel(const int* __restrict__ ei, int* __restrict__ bcursor,
                           unsigned int* __restrict__ bins) {
    __shared__ int cnt[NBUCK];
    __shared__ int base[NBUCK];
    const int tid = threadIdx.x;
    const int e0 = blockIdx.x * CH;

    for (int i = tid; i < NBUCK; i += 256) cnt[i] = 0;
    __syncthreads();

    int src[8], dstl[8], nb[8];
    #pragma unroll
    for (int i = 0; i < 8; ++i) {
        const int e = e0 + i * 256 + tid;
        if (e < NEDGES) {
            src[i] = ei[e];
            const int d = ei[NEDGES + e];
            dstl[i] = d & BMASK;
            nb[i] = d >> BSHIFT;
        } else {
            nb[i] = -1;
        }
    }
    #pragma unroll
    for (int i = 0; i < 8; ++i)
        if (nb[i] >= 0) atomicAdd(&cnt[nb[i]], 1);
    __syncthreads();

    for (int b = tid; b < NBUCK; b += 256) {
        base[b] = (cnt[b] > 0) ? atomicAdd(&bcursor[b], cnt[b]) : 0;
        cnt[b] = 0;   // reuse as local offset
    }
    __syncthreads();

    #pragma unroll
    for (int i = 0; i < 8; ++i) {
        if (nb[i] >= 0) {
            const int off = atomicAdd(&cnt[nb[i]], 1);
            const int pos = base[nb[i]] + off;
            if (pos < (nb[i] + 1) * BCAP)
                bins[pos] = ((unsigned)src[i] << BSHIFT) | (unsigned)dstl[i];
        }
    }
}

// per-bucket histogram -> deg written coalesced (no global atomics)
__global__ void count_kernel(const unsigned int* __restrict__ bins,
                             const int* __restrict__ bcursor, int* __restrict__ deg) {
    __shared__ int cnt[128];
    const int b = blockIdx.x;
    const int tid = threadIdx.x;
    if (tid < 128) cnt[tid] = 0;
    __syncthreads();
    int n = bcursor[b] - b * BCAP;
    if (n > BCAP) n = BCAP;
    const unsigned int* p = bins + (size_t)b * BCAP;
    for (int i = tid; i < n; i += 256) atomicAdd(&cnt[p[i] & BMASK], 1);
    __syncthreads();
    if (tid < 128) deg[b * 128 + tid] = cnt[tid];
}

// --- hierarchical exclusive scan of deg -> rowstart ------------------------
__global__ void scan_part1(const int* __restrict__ deg, int* __restrict__ excl,
                           int* __restrict__ partials) {
    __shared__ int sm[256];
    const int t = threadIdx.x;
    const int i = blockIdx.x * 256 + t;
    const int v = (i < NNODES) ? deg[i] : 0;
    sm[t] = v;
    __syncthreads();
    #pragma unroll
    for (int off = 1; off < 256; off <<= 1) {
        const int cur = sm[t];
        const int add = (t >= off) ? sm[t - off] : 0;
        __syncthreads();
        sm[t] = cur + add;
        __syncthreads();
    }
    excl[i] = sm[t] - v;
    if (t == 255) partials[blockIdx.x] = sm[255];
}

__global__ void scan_part2(const int* __restrict__ partials, int* __restrict__ blockbase) {
    __shared__ int sm[256];
    const int t = threadIdx.x;
    const int v = (t < SCAN_BLOCKS) ? partials[t] : 0;
    sm[t] = v;
    __syncthreads();
    #pragma unroll
    for (int off = 1; off < 256; off <<= 1) {
        const int cur = sm[t];
        const int add = (t >= off) ? sm[t - off] : 0;
        __syncthreads();
        sm[t] = cur + add;
        __syncthreads();
    }
    blockbase[t] = sm[t] - v;
}

__global__ void scan_part3(const int* __restrict__ excl, const int* __restrict__ blockbase,
                           int* __restrict__ rowstart) {
    const int i = blockIdx.x * 256 + threadIdx.x;
    if (i < NNODES) rowstart[i] = blockbase[blockIdx.x] + excl[i];
}

// per-bucket placement: scatter within a ~4KB ebuf window (single block/CU)
__global__ void place_kernel(const unsigned int* __restrict__ bins,
                             const int* __restrict__ bcursor,
                             const int* __restrict__ rowstart,
                             unsigned short* __restrict__ ebuf) {
    __shared__ int lcur[128];
    const int b = blockIdx.x;
    const int tid = threadIdx.x;
    if (tid < 128) {
        const int node = b * 128 + tid;
        lcur[tid] = (node < NNODES) ? rowstart[node] : 0;
    }
    __syncthreads();
    int n = bcursor[b] - b * BCAP;
    if (n > BCAP) n = BCAP;
    const unsigned int* p = bins + (size_t)b * BCAP;
    for (int i = tid; i < n; i += 256) {
        const unsigned v = p[i];
        const int pos = atomicAdd(&lcur[v & BMASK], 1);
        ebuf[pos] = (unsigned short)(v >> BSHIFT);
    }
}

// ---------------------------------------------------------------------------
// y1 = bf16(x @ Wa)   (tile 64 rows x 128 cols, 256 thr, 4x8 per thread)
__global__ void gemm_y1_kernel(const float* __restrict__ x, const float* __restrict__ Wa,
                               unsigned short* __restrict__ y1) {
    __shared__ float sA[64 * 132];
    __shared__ float sW[32 * 128];
    const int tid = threadIdx.x;
    const int rbase = blockIdx.x * 64;
    const int colgrp = tid & 15;
    const int rowgrp = tid >> 4;
    const int c0 = colgrp * 8;

    #pragma unroll
    for (int i = 0; i < 8; ++i) {
        const int f = tid + i * 256;
        const int row = f >> 5, c4 = f & 31;
        int rg = rbase + row;
        if (rg > NNODES - 1) rg = NNODES - 1;
        *(float4*)&sA[row * 132 + c4 * 4] = *(const float4*)&x[(size_t)rg * D + c4 * 4];
    }

    float acc[4][8];
    #pragma unroll
    for (int r = 0; r < 4; ++r)
        #pragma unroll
        for (int j = 0; j < 8; ++j) acc[r][j] = 0.0f;

    for (int kq = 0; kq < 4; ++kq) {
        __syncthreads();
        #pragma unroll
        for (int i = 0; i < 4; ++i) {
            const int f = tid + i * 256;
            const int kr = f >> 5, c4 = f & 31;
            *(float4*)&sW[kr * 128 + c4 * 4] =
                *(const float4*)&Wa[(kq * 32 + kr) * D + c4 * 4];
        }
        __syncthreads();
        #pragma unroll
        for (int k = 0; k < 32; k += 4) {
            const int kg = kq * 32 + k;
            float a0[4], a1[4], a2[4], a3[4];
            *(float4*)a0 = *(const float4*)&sA[(rowgrp * 4 + 0) * 132 + kg];
            *(float4*)a1 = *(const float4*)&sA[(rowgrp * 4 + 1) * 132 + kg];
            *(float4*)a2 = *(const float4*)&sA[(rowgrp * 4 + 2) * 132 + kg];
            *(float4*)a3 = *(const float4*)&sA[(rowgrp * 4 + 3) * 132 + kg];
            #pragma unroll
            for (int dk = 0; dk < 4; ++dk) {
                float w[8];
                *(float4*)&w[0] = *(const float4*)&sW[(k + dk) * 128 + c0];
                *(float4*)&w[4] = *(const float4*)&sW[(k + dk) * 128 + c0 + 4];
                #pragma unroll
                for (int j = 0; j < 8; ++j) {
                    acc[0][j] = fmaf(a0[dk], w[j], acc[0][j]);
                    acc[1][j] = fmaf(a1[dk], w[j], acc[1][j]);
                    acc[2][j] = fmaf(a2[dk], w[j], acc[2][j]);
                    acc[3][j] = fmaf(a3[dk], w[j], acc[3][j]);
                }
            }
        }
    }

    #pragma unroll
    for (int r = 0; r < 4; ++r) {
        const int row = rbase + rowgrp * 4 + r;
        if (row < NNODES) {
            ushort8 o;
            #pragma unroll
            for (int j = 0; j < 8; ++j) o[j] = f32_to_bf16(acc[r][j]);
            *(ushort8*)&y1[(size_t)row * D + c0] = o;
        }
    }
}

// ---------------------------------------------------------------------------
#define ACC8(q)                                                        \
    do {                                                               \
        a[0] += __uint_as_float((q).x << 16);                          \
        a[1] += __uint_as_float((q).x & 0xffff0000u);                  \
        a[2] += __uint_as_float((q).y << 16);                          \
        a[3] += __uint_as_float((q).y & 0xffff0000u);                  \
        a[4] += __uint_as_float((q).z << 16);                          \
        a[5] += __uint_as_float((q).z & 0xffff0000u);                  \
        a[6] += __uint_as_float((q).w << 16);                          \
        a[7] += __uint_as_float((q).w & 0xffff0000u);                  \
    } while (0)

// Fused: h1 = relu(mean_agg(y1)+ba) -> LDS (f32); y2 = bf16(h1 @ W2)
// block = 256 thr = 16 nodes x 16 lanes
__global__ void gather1_gemm2_kernel(const uint4* __restrict__ y1,
                                     const int* __restrict__ rowstart,
                                     const int* __restrict__ deg,
                                     const unsigned short* __restrict__ ebuf,
                                     const float* __restrict__ ba,
                                     const float* __restrict__ W2,
                                     unsigned short* __restrict__ y2) {
    __shared__ float h1s[NPB][132];   // reads are nloc-broadcast: conflict-free
    __shared__ float w2s[32][129];    // stride 129 -> read bank = sub+kk: conflict-free
    const int tid = threadIdx.x;
    const int nloc = tid >> 4;        // 0..15
    const int sub = tid & 15;         // 0..15
    const int node = blockIdx.x * NPB + nloc;

    // ---- phase 1: gather + mean + bias + relu -> h1s (f32) ----
    const int beg = rowstart[node];
    const int cnt = deg[node];
    float a[8];
    {
        const uint4 q = y1[(size_t)node * 16 + sub];   // self loop
        a[0] = __uint_as_float(q.x << 16);  a[1] = __uint_as_float(q.x & 0xffff0000u);
        a[2] = __uint_as_float(q.y << 16);  a[3] = __uint_as_float(q.y & 0xffff0000u);
        a[4] = __uint_as_float(q.z << 16);  a[5] = __uint_as_float(q.z & 0xffff0000u);
        a[6] = __uint_as_float(q.w << 16);  a[7] = __uint_as_float(q.w & 0xffff0000u);
    }
    const unsigned short* nb = ebuf + beg;
    int k = 0;
    for (; k + 4 <= cnt; k += 4) {
        const int s0 = nb[k], s1 = nb[k + 1], s2 = nb[k + 2], s3 = nb[k + 3];
        const uint4 q0 = y1[(size_t)s0 * 16 + sub];
        const uint4 q1 = y1[(size_t)s1 * 16 + sub];
        const uint4 q2 = y1[(size_t)s2 * 16 + sub];
        const uint4 q3 = y1[(size_t)s3 * 16 + sub];
        ACC8(q0); ACC8(q1); ACC8(q2); ACC8(q3);
    }
    for (; k < cnt; ++k) {
        const uint4 q = y1[(size_t)nb[k] * 16 + sub];
        ACC8(q);
    }
    const float inv = 1.0f / (float)(cnt + 1);
    #pragma unroll
    for (int j = 0; j < 8; ++j)
        h1s[nloc][sub * 8 + j] = fmaxf(fmaf(a[j], inv, ba[sub * 8 + j]), 0.0f);

    // ---- phase 2: y2 = h1 @ W2 in two 32-col halves ----
    for (int kh = 0; kh < 2; ++kh) {
        __syncthreads();              // h1s ready / previous half consumed
        #pragma unroll
        for (int i = 0; i < 4; ++i) {
            const int f = tid + i * 256;      // 1024 float4 slots = 128 rows x 8
            const int kk = f >> 3;            // 0..127
            const int c4 = f & 7;             // 0..7
            const float4 w = *(const float4*)&W2[kk * DOUT + kh * 32 + c4 * 4];
            w2s[c4 * 4 + 0][kk] = w.x;
            w2s[c4 * 4 + 1][kk] = w.y;
            w2s[c4 * 4 + 2][kk] = w.z;
            w2s[c4 * 4 + 3][kk] = w.w;
        }
        __syncthreads();
        float acc0 = 0.0f, acc1 = 0.0f;
        #pragma unroll
        for (int kk = 0; kk < D; kk += 4) {
            const float4 hv = *(const float4*)&h1s[nloc][kk];
            acc0 = fmaf(hv.x, w2s[sub][kk + 0],
                   fmaf(hv.y, w2s[sub][kk + 1],
                   fmaf(hv.z, w2s[sub][kk + 2],
                   fmaf(hv.w, w2s[sub][kk + 3], acc0))));
            acc1 = fmaf(hv.x, w2s[sub + 16][kk + 0],
                   fmaf(hv.y, w2s[sub + 16][kk + 1],
                   fmaf(hv.z, w2s[sub + 16][kk + 2],
                   fmaf(hv.w, w2s[sub + 16][kk + 3], acc1))));
        }
        y2[(size_t)node * DOUT + kh * 32 + sub]      = f32_to_bf16(acc0);
        y2[(size_t)node * DOUT + kh * 32 + sub + 16] = f32_to_bf16(acc1);
    }
}

// out = rownorm(mean_agg(y2) + b2): 8 lanes/node, one uint4 (8 bf16) per lane
__global__ void gather2_kernel(const uint4* __restrict__ y2, const int* __restrict__ rowstart,
                               const int* __restrict__ deg, const unsigned short* __restrict__ ebuf,
                               const float* __restrict__ b2, float* __restrict__ out) {
    const int gid = blockIdx.x * blockDim.x + threadIdx.x;
    const int node = gid >> 3;
    const int sub = gid & 7;
    if (node >= NNODES) return;
    const int beg = rowstart[node];
    const int cnt = deg[node];
    float a[8];
    {
        const uint4 q = y2[(size_t)node * 8 + sub];
        a[0] = __uint_as_float(q.x << 16);  a[1] = __uint_as_float(q.x & 0xffff0000u);
        a[2] = __uint_as_float(q.y << 16);  a[3] = __uint_as_float(q.y & 0xffff0000u);
        a[4] = __uint_as_float(q.z << 16);  a[5] = __uint_as_float(q.z & 0xffff0000u);
        a[6] = __uint_as_float(q.w << 16);  a[7] = __uint_as_float(q.w & 0xffff0000u);
    }
    const unsigned short* nb = ebuf + beg;
    int k = 0;
    for (; k + 4 <= cnt; k += 4) {
        const int s0 = nb[k], s1 = nb[k + 1], s2 = nb[k + 2], s3 = nb[k + 3];
        const uint4 q0 = y2[(size_t)s0 * 8 + sub];
        const uint4 q1 = y2[(size_t)s1 * 8 + sub];
        const uint4 q2 = y2[(size_t)s2 * 8 + sub];
        const uint4 q3 = y2[(size_t)s3 * 8 + sub];
        ACC8(q0); ACC8(q1); ACC8(q2); ACC8(q3);
    }
    for (; k < cnt; ++k) {
        const uint4 q = y2[(size_t)nb[k] * 8 + sub];
        ACC8(q);
    }
    const float inv = 1.0f / (float)(cnt + 1);
    float v[8];
    float ss = 0.0f;
    #pragma unroll
    for (int j = 0; j < 8; ++j) {
        v[j] = fmaf(a[j], inv, b2[sub * 8 + j]);
        ss = fmaf(v[j], v[j], ss);
    }
    ss += __shfl_xor(ss, 1);
    ss += __shfl_xor(ss, 2);
    ss += __shfl_xor(ss, 4);
    const float scale = 1.0f / fmaxf(sqrtf(ss), 1e-12f);
    float o[8];
    #pragma unroll
    for (int j = 0; j < 8; ++j) o[j] = v[j] * scale;
    float* dst = &out[(size_t)node * DOUT + sub * 8];
    *(float4*)&dst[0] = *(const float4*)&o[0];
    *(float4*)&dst[4] = *(const float4*)&o[4];
}

// ---------------------------------------------------------------------------
extern "C" void kernel_launch(void* const* d_in, const int* in_sizes, int n_in,
                              void* d_out, int out_size, void* d_ws, size_t ws_size,
                              hipStream_t stream) {
    const float* x    = (const float*)d_in[0];
    const int*   ei   = (const int*)d_in[1];
    const float* Wpre = (const float*)d_in[2];
    const float* bpre = (const float*)d_in[3];
    const float* W1   = (const float*)d_in[4];
    const float* b1   = (const float*)d_in[5];
    const float* W2   = (const float*)d_in[6];
    const float* b2   = (const float*)d_in[7];
    float* out = (float*)d_out;

    // workspace layout (~25.5 MB)
    char* ws = (char*)d_ws;
    unsigned short* y1   = (unsigned short*)ws;                 // [N*128] bf16 = 12.8 MB
    unsigned short* y2   = (unsigned short*)(ws + 12800000);    // [N*64]  bf16 = 6.4 MB
    int* deg             = (int*)(ws + 19200000);               // [50176]
    int* rowstart        = (int*)(ws + 19400704);               // [50176]
    unsigned short* ebuf = (unsigned short*)(ws + 19601408);    // [E] ushort = 1.6 MB
    unsigned int* bins   = (unsigned int*)(ws + 21201408);      // [NBUCK*BCAP] = 4.0 MB
    int* bcursor         = (int*)(ws + 25205248);               // [NBUCK]
    int* excl            = (int*)(ws + 25207296);               // [SCAN_BLOCKS*256]
    int* partials        = (int*)(ws + 25408000);               // [256]
    int* blockbase       = (int*)(ws + 25409024);               // [256]
    float* Wa            = (float*)(ws + 25410048);             // [128*128]
    float* ba            = (float*)(ws + 25475584);             // [128]

    // binned CSR build (no random-scatter passes)
    binit_kernel<<<2, 256, 0, stream>>>(bcursor);
    bin_kernel<<<(NEDGES + CH - 1) / CH, 256, 0, stream>>>(ei, bcursor, bins);
    count_kernel<<<NBUCK, 256, 0, stream>>>(bins, bcursor, deg);
    scan_part1<<<SCAN_BLOCKS, 256, 0, stream>>>(deg, excl, partials);
    scan_part2<<<1, 256, 0, stream>>>(partials, blockbase);
    scan_part3<<<SCAN_BLOCKS, 256, 0, stream>>>(excl, blockbase, rowstart);
    place_kernel<<<NBUCK, 256, 0, stream>>>(bins, bcursor, rowstart, ebuf);

    // folded weights
    combine_w_kernel<<<D + 1, D, 0, stream>>>(Wpre, bpre, W1, b1, Wa, ba);

    // layer 1: y1 = bf16(x @ Wa)
    gemm_y1_kernel<<<(NNODES + 63) / 64, 256, 0, stream>>>(x, Wa, y1);

    // fused: h1 = relu(mean_agg(y1)+ba) in LDS; y2 = bf16(h1 @ W2)
    gather1_gemm2_kernel<<<NNODES / NPB, 256, 0, stream>>>(
        (const uint4*)y1, rowstart, deg, ebuf, ba, W2, y2);

    // layer 2 aggregate + normalize
    gather2_kernel<<<(NNODES * 8 + 255) / 256, 256, 0, stream>>>(
        (const uint4*)y2, rowstart, deg, ebuf, b2, out);
}

// Round 8
// 214.836 us; speedup vs baseline: 13.3873x; 1.0057x over previous
//
#include <hip/hip_runtime.h>
#include <hip/hip_bf16.h>

#define NNODES 50000
#define NEDGES 800000
#define D 128
#define DOUT 64
#define SCAN_BLOCKS 196   // 196*256 = 50176 >= NNODES
#define NPB 16            // nodes per block in fused gather1+gemm2

// binned CSR build
#define BSHIFT 7
#define BMASK 127
#define NBUCK 391         // ceil(50000/128)
#define BCAP 2560         // bucket capacity (mean 2048, sigma~45 -> >11 sigma)
#define CH 2048           // edges per bin block

typedef unsigned short ushort8 __attribute__((ext_vector_type(8)));

__device__ inline unsigned short f32_to_bf16(float f) {
    unsigned u = __float_as_uint(f);
    u = (u + 0x7fffu + ((u >> 16) & 1u)) >> 16;   // round-to-nearest-even
    return (unsigned short)u;
}

// ---------------------------------------------------------------------------
// Wa = Wpre @ W1 (128x128), ba = bpre @ W1 + b1 (128)
__global__ void combine_w_kernel(const float* __restrict__ Wpre, const float* __restrict__ bpre,
                                 const float* __restrict__ W1, const float* __restrict__ b1,
                                 float* __restrict__ Wa, float* __restrict__ ba) {
    const int j = threadIdx.x;
    const int i = blockIdx.x;
    if (i < D) {
        float s = 0.0f;
        for (int k = 0; k < D; ++k) s = fmaf(Wpre[i * D + k], W1[k * D + j], s);
        Wa[i * D + j] = s;
    } else {
        float s = b1[j];
        for (int k = 0; k < D; ++k) s = fmaf(bpre[k], W1[k * D + j], s);
        ba[j] = s;
    }
}

// --- binned CSR build ------------------------------------------------------
__global__ void binit_kernel(int* __restrict__ bcursor) {
    const int b = blockIdx.x * 256 + threadIdx.x;
    if (b < NBUCK) bcursor[b] = b * BCAP;
}

// bin edges by dst>>7 into fixed-capacity bucket regions.
__global__ void bin_kernel(const int* __restrict__ ei, int* __restrict__ bcursor,
                           unsigned int* __restrict__ bins) {
    __shared__ int cnt[NBUCK];
    __shared__ int base[NBUCK];
    const int tid = threadIdx.x;
    const int e0 = blockIdx.x * CH;

    for (int i = tid; i < NBUCK; i += 256) cnt[i] = 0;
    __syncthreads();

    int src[8], dstl[8], nb[8];
    #pragma unroll
    for (int i = 0; i < 8; ++i) {
        const int e = e0 + i * 256 + tid;
        if (e < NEDGES) {
            src[i] = ei[e];
            const int d = ei[NEDGES + e];
            dstl[i] = d & BMASK;
            nb[i] = d >> BSHIFT;
        } else {
            nb[i] = -1;
        }
    }
    #pragma unroll
    for (int i = 0; i < 8; ++i)
        if (nb[i] >= 0) atomicAdd(&cnt[nb[i]], 1);
    __syncthreads();

    for (int b = tid; b < NBUCK; b += 256) {
        base[b] = (cnt[b] > 0) ? atomicAdd(&bcursor[b], cnt[b]) : 0;
        cnt[b] = 0;   // reuse as local offset
    }
    __syncthreads();

    #pragma unroll
    for (int i = 0; i < 8; ++i) {
        if (nb[i] >= 0) {
            const int off = atomicAdd(&cnt[nb[i]], 1);
            const int pos = base[nb[i]] + off;
            if (pos < (nb[i] + 1) * BCAP)
                bins[pos] = ((unsigned)src[i] << BSHIFT) | (unsigned)dstl[i];
        }
    }
}

// per-bucket histogram -> deg written coalesced (no global atomics)
__global__ void count_kernel(const unsigned int* __restrict__ bins,
                             const int* __restrict__ bcursor, int* __restrict__ deg) {
    __shared__ int cnt[128];
    const int b = blockIdx.x;
    const int tid = threadIdx.x;
    if (tid < 128) cnt[tid] = 0;
    __syncthreads();
    int n = bcursor[b] - b * BCAP;
    if (n > BCAP) n = BCAP;
    const unsigned int* p = bins + (size_t)b * BCAP;
    for (int i = tid; i < n; i += 256) atomicAdd(&cnt[p[i] & BMASK], 1);
    __syncthreads();
    if (tid < 128) deg[b * 128 + tid] = cnt[tid];
}

// --- hierarchical exclusive scan of deg -> rowstart ------------------------
__global__ void scan_part1(const int* __restrict__ deg, int* __restrict__ excl,
                           int* __restrict__ partials) {
    __shared__ int sm[256];
    const int t = threadIdx.x;
    const int i = blockIdx.x * 256 + t;
    const int v = (i < NNODES) ? deg[i] : 0;
    sm[t] = v;
    __syncthreads();
    #pragma unroll
    for (int off = 1; off < 256; off <<= 1) {
        const int cur = sm[t];
        const int add = (t >= off) ? sm[t - off] : 0;
        __syncthreads();
        sm[t] = cur + add;
        __syncthreads();
    }
    excl[i] = sm[t] - v;
    if (t == 255) partials[blockIdx.x] = sm[255];
}

__global__ void scan_part2(const int* __restrict__ partials, int* __restrict__ blockbase) {
    __shared__ int sm[256];
    const int t = threadIdx.x;
    const int v = (t < SCAN_BLOCKS) ? partials[t] : 0;
    sm[t] = v;
    __syncthreads();
    #pragma unroll
    for (int off = 1; off < 256; off <<= 1) {
        const int cur = sm[t];
        const int add = (t >= off) ? sm[t - off] : 0;
        __syncthreads();
        sm[t] = cur + add;
        __syncthreads();
    }
    blockbase[t] = sm[t] - v;
}

__global__ void scan_part3(const int* __restrict__ excl, const int* __restrict__ blockbase,
                           int* __restrict__ rowstart) {
    const int i = blockIdx.x * 256 + threadIdx.x;
    if (i < NNODES) rowstart[i] = blockbase[blockIdx.x] + excl[i];
    if (blockIdx.x == 0 && threadIdx.x == 0) rowstart[NNODES] = NEDGES;
}

// per-bucket placement: scatter within a ~4KB ebuf window
__global__ void place_kernel(const unsigned int* __restrict__ bins,
                             const int* __restrict__ bcursor,
                             const int* __restrict__ rowstart,
                             unsigned short* __restrict__ ebuf) {
    __shared__ int lcur[128];
    const int b = blockIdx.x;
    const int tid = threadIdx.x;
    if (tid < 128) {
        const int node = b * 128 + tid;
        lcur[tid] = (node < NNODES) ? rowstart[node] : 0;
    }
    __syncthreads();
    int n = bcursor[b] - b * BCAP;
    if (n > BCAP) n = BCAP;
    const unsigned int* p = bins + (size_t)b * BCAP;
    for (int i = tid; i < n; i += 256) {
        const unsigned v = p[i];
        const int pos = atomicAdd(&lcur[v & BMASK], 1);
        ebuf[pos] = (unsigned short)(v >> BSHIFT);
    }
}

// ---------------------------------------------------------------------------
// y1 = bf16(x @ Wa)   (tile 64 rows x 128 cols, 256 thr, 4x8 per thread)
__global__ void gemm_y1_kernel(const float* __restrict__ x, const float* __restrict__ Wa,
                               unsigned short* __restrict__ y1) {
    __shared__ float sA[64 * 132];
    __shared__ float sW[32 * 128];
    const int tid = threadIdx.x;
    const int rbase = blockIdx.x * 64;
    const int colgrp = tid & 15;
    const int rowgrp = tid >> 4;
    const int c0 = colgrp * 8;

    #pragma unroll
    for (int i = 0; i < 8; ++i) {
        const int f = tid + i * 256;
        const int row = f >> 5, c4 = f & 31;
        int rg = rbase + row;
        if (rg > NNODES - 1) rg = NNODES - 1;
        *(float4*)&sA[row * 132 + c4 * 4] = *(const float4*)&x[(size_t)rg * D + c4 * 4];
    }

    float acc[4][8];
    #pragma unroll
    for (int r = 0; r < 4; ++r)
        #pragma unroll
        for (int j = 0; j < 8; ++j) acc[r][j] = 0.0f;

    for (int kq = 0; kq < 4; ++kq) {
        __syncthreads();
        #pragma unroll
        for (int i = 0; i < 4; ++i) {
            const int f = tid + i * 256;
            const int kr = f >> 5, c4 = f & 31;
            *(float4*)&sW[kr * 128 + c4 * 4] =
                *(const float4*)&Wa[(kq * 32 + kr) * D + c4 * 4];
        }
        __syncthreads();
        #pragma unroll
        for (int k = 0; k < 32; k += 4) {
            const int kg = kq * 32 + k;
            float a0[4], a1[4], a2[4], a3[4];
            *(float4*)a0 = *(const float4*)&sA[(rowgrp * 4 + 0) * 132 + kg];
            *(float4*)a1 = *(const float4*)&sA[(rowgrp * 4 + 1) * 132 + kg];
            *(float4*)a2 = *(const float4*)&sA[(rowgrp * 4 + 2) * 132 + kg];
            *(float4*)a3 = *(const float4*)&sA[(rowgrp * 4 + 3) * 132 + kg];
            #pragma unroll
            for (int dk = 0; dk < 4; ++dk) {
                float w[8];
                *(float4*)&w[0] = *(const float4*)&sW[(k + dk) * 128 + c0];
                *(float4*)&w[4] = *(const float4*)&sW[(k + dk) * 128 + c0 + 4];
                #pragma unroll
                for (int j = 0; j < 8; ++j) {
                    acc[0][j] = fmaf(a0[dk], w[j], acc[0][j]);
                    acc[1][j] = fmaf(a1[dk], w[j], acc[1][j]);
                    acc[2][j] = fmaf(a2[dk], w[j], acc[2][j]);
                    acc[3][j] = fmaf(a3[dk], w[j], acc[3][j]);
                }
            }
        }
    }

    #pragma unroll
    for (int r = 0; r < 4; ++r) {
        const int row = rbase + rowgrp * 4 + r;
        if (row < NNODES) {
            ushort8 o;
            #pragma unroll
            for (int j = 0; j < 8; ++j) o[j] = f32_to_bf16(acc[r][j]);
            *(ushort8*)&y1[(size_t)row * D + c0] = o;
        }
    }
}

// ---------------------------------------------------------------------------
#define ACC8(q)                                                        \
    do {                                                               \
        a[0] += __uint_as_float((q).x << 16);                          \
        a[1] += __uint_as_float((q).x & 0xffff0000u);                  \
        a[2] += __uint_as_float((q).y << 16);                          \
        a[3] += __uint_as_float((q).y & 0xffff0000u);                  \
        a[4] += __uint_as_float((q).z << 16);                          \
        a[5] += __uint_as_float((q).z & 0xffff0000u);                  \
        a[6] += __uint_as_float((q).w << 16);                          \
        a[7] += __uint_as_float((q).w & 0xffff0000u);                  \
    } while (0)

// Fused: h1 = relu(mean_agg(y1)+ba) -> LDS (f32); y2 = bf16(h1 @ W2)
// block = 256 thr = 16 nodes x 16 lanes. LDS 16.9KB -> 8 blocks/CU (wave cap)
__global__ void gather1_gemm2_kernel(const uint4* __restrict__ y1,
                                     const int* __restrict__ rowstart,
                                     const unsigned short* __restrict__ ebuf,
                                     const float* __restrict__ ba,
                                     const float* __restrict__ W2,
                                     unsigned short* __restrict__ y2) {
    __shared__ float h1s[NPB][132];   // reads are nloc-broadcast: conflict-free
    __shared__ float w2s[16][132];    // float4 reads: 2-way aliasing = free (m136)
    const int tid = threadIdx.x;
    const int nloc = tid >> 4;        // 0..15
    const int sub = tid & 15;         // 0..15
    const int node = blockIdx.x * NPB + nloc;

    // ---- phase 1: gather + mean + bias + relu -> h1s (f32) ----
    const int beg = rowstart[node];
    const int cnt = rowstart[node + 1] - beg;
    float a[8];
    {
        const uint4 q = y1[(size_t)node * 16 + sub];   // self loop
        a[0] = __uint_as_float(q.x << 16);  a[1] = __uint_as_float(q.x & 0xffff0000u);
        a[2] = __uint_as_float(q.y << 16);  a[3] = __uint_as_float(q.y & 0xffff0000u);
        a[4] = __uint_as_float(q.z << 16);  a[5] = __uint_as_float(q.z & 0xffff0000u);
        a[6] = __uint_as_float(q.w << 16);  a[7] = __uint_as_float(q.w & 0xffff0000u);
    }
    const unsigned short* nb = ebuf + beg;
    int k = 0;
    for (; k + 4 <= cnt; k += 4) {
        const int s0 = nb[k], s1 = nb[k + 1], s2 = nb[k + 2], s3 = nb[k + 3];
        const uint4 q0 = y1[(size_t)s0 * 16 + sub];
        const uint4 q1 = y1[(size_t)s1 * 16 + sub];
        const uint4 q2 = y1[(size_t)s2 * 16 + sub];
        const uint4 q3 = y1[(size_t)s3 * 16 + sub];
        ACC8(q0); ACC8(q1); ACC8(q2); ACC8(q3);
    }
    for (; k < cnt; ++k) {
        const uint4 q = y1[(size_t)nb[k] * 16 + sub];
        ACC8(q);
    }
    const float inv = 1.0f / (float)(cnt + 1);
    #pragma unroll
    for (int j = 0; j < 8; ++j)
        h1s[nloc][sub * 8 + j] = fmaxf(fmaf(a[j], inv, ba[sub * 8 + j]), 0.0f);

    // ---- phase 2: y2 = h1 @ W2 in four 16-col quarters ----
    for (int q = 0; q < 4; ++q) {
        __syncthreads();              // h1s ready / previous quarter consumed
        #pragma unroll
        for (int i = 0; i < 2; ++i) {
            const int f = tid + i * 256;      // 512 float4 slots = 128 rows x 4
            const int kk = f >> 2;            // 0..127
            const int c4 = f & 3;             // 0..3
            const float4 w = *(const float4*)&W2[kk * DOUT + q * 16 + c4 * 4];
            w2s[c4 * 4 + 0][kk] = w.x;
            w2s[c4 * 4 + 1][kk] = w.y;
            w2s[c4 * 4 + 2][kk] = w.z;
            w2s[c4 * 4 + 3][kk] = w.w;
        }
        __syncthreads();
        float acc0 = 0.0f;
        #pragma unroll
        for (int kk = 0; kk < D; kk += 4) {
            const float4 hv = *(const float4*)&h1s[nloc][kk];
            const float4 w0 = *(const float4*)&w2s[sub][kk];
            acc0 = fmaf(hv.x, w0.x, fmaf(hv.y, w0.y, fmaf(hv.z, w0.z, fmaf(hv.w, w0.w, acc0))));
        }
        y2[(size_t)node * DOUT + q * 16 + sub] = f32_to_bf16(acc0);
    }
}

// out = rownorm(mean_agg(y2) + b2): 8 lanes/node, 8-deep load pipeline
__global__ void gather2_kernel(const uint4* __restrict__ y2, const int* __restrict__ rowstart,
                               const unsigned short* __restrict__ ebuf,
                               const float* __restrict__ b2, float* __restrict__ out) {
    const int gid = blockIdx.x * blockDim.x + threadIdx.x;
    const int node = gid >> 3;
    const int sub = gid & 7;
    if (node >= NNODES) return;
    const int beg = rowstart[node];
    const int cnt = rowstart[node + 1] - beg;
    float a[8];
    {
        const uint4 q = y2[(size_t)node * 8 + sub];
        a[0] = __uint_as_float(q.x << 16);  a[1] = __uint_as_float(q.x & 0xffff0000u);
        a[2] = __uint_as_float(q.y << 16);  a[3] = __uint_as_float(q.y & 0xffff0000u);
        a[4] = __uint_as_float(q.z << 16);  a[5] = __uint_as_float(q.z & 0xffff0000u);
        a[6] = __uint_as_float(q.w << 16);  a[7] = __uint_as_float(q.w & 0xffff0000u);
    }
    const unsigned short* nb = ebuf + beg;
    int k = 0;
    for (; k + 8 <= cnt; k += 8) {
        int s[8];
        #pragma unroll
        for (int i = 0; i < 8; ++i) s[i] = nb[k + i];
        uint4 q[8];
        #pragma unroll
        for (int i = 0; i < 8; ++i) q[i] = y2[(size_t)s[i] * 8 + sub];
        #pragma unroll
        for (int i = 0; i < 8; ++i) ACC8(q[i]);
    }
    for (; k < cnt; ++k) {
        const uint4 q = y2[(size_t)nb[k] * 8 + sub];
        ACC8(q);
    }
    const float inv = 1.0f / (float)(cnt + 1);
    float v[8];
    float ss = 0.0f;
    #pragma unroll
    for (int j = 0; j < 8; ++j) {
        v[j] = fmaf(a[j], inv, b2[sub * 8 + j]);
        ss = fmaf(v[j], v[j], ss);
    }
    ss += __shfl_xor(ss, 1);
    ss += __shfl_xor(ss, 2);
    ss += __shfl_xor(ss, 4);
    const float scale = 1.0f / fmaxf(sqrtf(ss), 1e-12f);
    float o[8];
    #pragma unroll
    for (int j = 0; j < 8; ++j) o[j] = v[j] * scale;
    float* dst = &out[(size_t)node * DOUT + sub * 8];
    *(float4*)&dst[0] = *(const float4*)&o[0];
    *(float4*)&dst[4] = *(const float4*)&o[4];
}

// ---------------------------------------------------------------------------
extern "C" void kernel_launch(void* const* d_in, const int* in_sizes, int n_in,
                              void* d_out, int out_size, void* d_ws, size_t ws_size,
                              hipStream_t stream) {
    const float* x    = (const float*)d_in[0];
    const int*   ei   = (const int*)d_in[1];
    const float* Wpre = (const float*)d_in[2];
    const float* bpre = (const float*)d_in[3];
    const float* W1   = (const float*)d_in[4];
    const float* b1   = (const float*)d_in[5];
    const float* W2   = (const float*)d_in[6];
    const float* b2   = (const float*)d_in[7];
    float* out = (float*)d_out;

    // workspace layout (~25.5 MB)
    char* ws = (char*)d_ws;
    unsigned short* y1   = (unsigned short*)ws;                 // [N*128] bf16 = 12.8 MB
    unsigned short* y2   = (unsigned short*)(ws + 12800000);    // [N*64]  bf16 = 6.4 MB
    int* deg             = (int*)(ws + 19200000);               // [50176]
    int* rowstart        = (int*)(ws + 19400704);               // [50176] (N+1 used)
    unsigned short* ebuf = (unsigned short*)(ws + 19601408);    // [E] ushort = 1.6 MB
    unsigned int* bins   = (unsigned int*)(ws + 21201408);      // [NBUCK*BCAP] = 4.0 MB
    int* bcursor         = (int*)(ws + 25205248);               // [NBUCK]
    int* excl            = (int*)(ws + 25207296);               // [SCAN_BLOCKS*256]
    int* partials        = (int*)(ws + 25408000);               // [256]
    int* blockbase       = (int*)(ws + 25409024);               // [256]
    float* Wa            = (float*)(ws + 25410048);             // [128*128]
    float* ba            = (float*)(ws + 25475584);             // [128]

    // binned CSR build (no random-scatter passes)
    binit_kernel<<<2, 256, 0, stream>>>(bcursor);
    bin_kernel<<<(NEDGES + CH - 1) / CH, 256, 0, stream>>>(ei, bcursor, bins);
    count_kernel<<<NBUCK, 256, 0, stream>>>(bins, bcursor, deg);
    scan_part1<<<SCAN_BLOCKS, 256, 0, stream>>>(deg, excl, partials);
    scan_part2<<<1, 256, 0, stream>>>(partials, blockbase);
    scan_part3<<<SCAN_BLOCKS, 256, 0, stream>>>(excl, blockbase, rowstart);
    place_kernel<<<NBUCK, 256, 0, stream>>>(bins, bcursor, rowstart, ebuf);

    // folded weights
    combine_w_kernel<<<D + 1, D, 0, stream>>>(Wpre, bpre, W1, b1, Wa, ba);

    // layer 1: y1 = bf16(x @ Wa)
    gemm_y1_kernel<<<(NNODES + 63) / 64, 256, 0, stream>>>(x, Wa, y1);

    // fused: h1 = relu(mean_agg(y1)+ba) in LDS; y2 = bf16(h1 @ W2)
    gather1_gemm2_kernel<<<NNODES / NPB, 256, 0, stream>>>(
        (const uint4*)y1, rowstart, ebuf, ba, W2, y2);

    // layer 2 aggregate + normalize
    gather2_kernel<<<(NNODES * 8 + 255) / 256, 256, 0, stream>>>(
        (const uint4*)y2, rowstart, ebuf, b2, out);
}

// Round 9
// 196.448 us; speedup vs baseline: 14.6404x; 1.0936x over previous
//
#include <hip/hip_runtime.h>
#include <hip/hip_bf16.h>

#define NNODES 50000
#define NEDGES 800000
#define D 128
#define DOUT 64
#define SCAN_BLOCKS 196   // 196*256 = 50176 >= NNODES
#define NPB 16            // nodes per block in fused gather1+gemm2

// binned CSR build
#define BSHIFT 7
#define BMASK 127
#define NBUCK 391         // ceil(50000/128)
#define BCAP 2560         // bucket capacity (mean 2048, sigma~45 -> >11 sigma)
#define CH 2048           // edges per bin block

typedef unsigned short ushort8 __attribute__((ext_vector_type(8)));
typedef short bf16x8 __attribute__((ext_vector_type(8)));
typedef float f32x4 __attribute__((ext_vector_type(4)));

__device__ inline unsigned short f32_to_bf16(float f) {
    unsigned u = __float_as_uint(f);
    u = (u + 0x7fffu + ((u >> 16) & 1u)) >> 16;   // round-to-nearest-even
    return (unsigned short)u;
}

// ---------------------------------------------------------------------------
// waT[c][k] = bf16((Wpre @ W1)[k][c]);  ba = bpre @ W1 + b1 (f32)
__global__ void combine_w_kernel(const float* __restrict__ Wpre, const float* __restrict__ bpre,
                                 const float* __restrict__ W1, const float* __restrict__ b1,
                                 unsigned short* __restrict__ waT, float* __restrict__ ba) {
    const int j = threadIdx.x;
    const int i = blockIdx.x;
    if (i < D) {
        float s = 0.0f;
        for (int k = 0; k < D; ++k) s = fmaf(Wpre[i * D + k], W1[k * D + j], s);
        waT[j * D + i] = f32_to_bf16(s);     // transposed store
    } else {
        float s = b1[j];
        for (int k = 0; k < D; ++k) s = fmaf(bpre[k], W1[k * D + j], s);
        ba[j] = s;
    }
}

// --- binned CSR build ------------------------------------------------------
__global__ void binit_kernel(int* __restrict__ bcursor) {
    const int b = blockIdx.x * 256 + threadIdx.x;
    if (b < NBUCK) bcursor[b] = b * BCAP;
}

__global__ void bin_kernel(const int* __restrict__ ei, int* __restrict__ bcursor,
                           unsigned int* __restrict__ bins) {
    __shared__ int cnt[NBUCK];
    __shared__ int base[NBUCK];
    const int tid = threadIdx.x;
    const int e0 = blockIdx.x * CH;

    for (int i = tid; i < NBUCK; i += 256) cnt[i] = 0;
    __syncthreads();

    int src[8], dstl[8], nb[8];
    #pragma unroll
    for (int i = 0; i < 8; ++i) {
        const int e = e0 + i * 256 + tid;
        if (e < NEDGES) {
            src[i] = ei[e];
            const int d = ei[NEDGES + e];
            dstl[i] = d & BMASK;
            nb[i] = d >> BSHIFT;
        } else {
            nb[i] = -1;
        }
    }
    #pragma unroll
    for (int i = 0; i < 8; ++i)
        if (nb[i] >= 0) atomicAdd(&cnt[nb[i]], 1);
    __syncthreads();

    for (int b = tid; b < NBUCK; b += 256) {
        base[b] = (cnt[b] > 0) ? atomicAdd(&bcursor[b], cnt[b]) : 0;
        cnt[b] = 0;   // reuse as local offset
    }
    __syncthreads();

    #pragma unroll
    for (int i = 0; i < 8; ++i) {
        if (nb[i] >= 0) {
            const int off = atomicAdd(&cnt[nb[i]], 1);
            const int pos = base[nb[i]] + off;
            if (pos < (nb[i] + 1) * BCAP)
                bins[pos] = ((unsigned)src[i] << BSHIFT) | (unsigned)dstl[i];
        }
    }
}

__global__ void count_kernel(const unsigned int* __restrict__ bins,
                             const int* __restrict__ bcursor, int* __restrict__ deg) {
    __shared__ int cnt[128];
    const int b = blockIdx.x;
    const int tid = threadIdx.x;
    if (tid < 128) cnt[tid] = 0;
    __syncthreads();
    int n = bcursor[b] - b * BCAP;
    if (n > BCAP) n = BCAP;
    const unsigned int* p = bins + (size_t)b * BCAP;
    for (int i = tid; i < n; i += 256) atomicAdd(&cnt[p[i] & BMASK], 1);
    __syncthreads();
    if (tid < 128) deg[b * 128 + tid] = cnt[tid];
}

// --- hierarchical exclusive scan of deg -> rowstart ------------------------
__global__ void scan_part1(const int* __restrict__ deg, int* __restrict__ excl,
                           int* __restrict__ partials) {
    __shared__ int sm[256];
    const int t = threadIdx.x;
    const int i = blockIdx.x * 256 + t;
    const int v = (i < NNODES) ? deg[i] : 0;
    sm[t] = v;
    __syncthreads();
    #pragma unroll
    for (int off = 1; off < 256; off <<= 1) {
        const int cur = sm[t];
        const int add = (t >= off) ? sm[t - off] : 0;
        __syncthreads();
        sm[t] = cur + add;
        __syncthreads();
    }
    excl[i] = sm[t] - v;
    if (t == 255) partials[blockIdx.x] = sm[255];
}

__global__ void scan_part2(const int* __restrict__ partials, int* __restrict__ blockbase) {
    __shared__ int sm[256];
    const int t = threadIdx.x;
    const int v = (t < SCAN_BLOCKS) ? partials[t] : 0;
    sm[t] = v;
    __syncthreads();
    #pragma unroll
    for (int off = 1; off < 256; off <<= 1) {
        const int cur = sm[t];
        const int add = (t >= off) ? sm[t - off] : 0;
        __syncthreads();
        sm[t] = cur + add;
        __syncthreads();
    }
    blockbase[t] = sm[t] - v;
}

__global__ void scan_part3(const int* __restrict__ excl, const int* __restrict__ blockbase,
                           int* __restrict__ rowstart) {
    const int i = blockIdx.x * 256 + threadIdx.x;
    if (i < NNODES) rowstart[i] = blockbase[blockIdx.x] + excl[i];
    if (blockIdx.x == 0 && threadIdx.x == 0) rowstart[NNODES] = NEDGES;
}

__global__ void place_kernel(const unsigned int* __restrict__ bins,
                             const int* __restrict__ bcursor,
                             const int* __restrict__ rowstart,
                             unsigned short* __restrict__ ebuf) {
    __shared__ int lcur[128];
    const int b = blockIdx.x;
    const int tid = threadIdx.x;
    if (tid < 128) {
        const int node = b * 128 + tid;
        lcur[tid] = (node < NNODES) ? rowstart[node] : 0;
    }
    __syncthreads();
    int n = bcursor[b] - b * BCAP;
    if (n > BCAP) n = BCAP;
    const unsigned int* p = bins + (size_t)b * BCAP;
    for (int i = tid; i < n; i += 256) {
        const unsigned v = p[i];
        const int pos = atomicAdd(&lcur[v & BMASK], 1);
        ebuf[pos] = (unsigned short)(v >> BSHIFT);
    }
}

// ---------------------------------------------------------------------------
// y1 = bf16(x @ Wa) via MFMA. Block: 256 thr = 4 waves, tile 64 rows x 128 cols.
// LDS pad +8 bf16 (stride 136): bank stride 4 -> 2-way aliasing (free, m136).
// Layouts (m89-verified C/D; standard CDNA A/B):
//   A: lane holds xs[row=l&15][k=(l>>4)*8+e];  B: waT[col=l&15][k=(l>>4)*8+e]
//   D: row=(l>>4)*4+reg, col=l&15
__global__ void __launch_bounds__(256) gemm_y1_mfma(const float* __restrict__ x,
                                                    const unsigned short* __restrict__ waT,
                                                    unsigned short* __restrict__ y1) {
    __shared__ unsigned short xs[64][136];
    __shared__ unsigned short wsm[128][136];
    const int tid = threadIdx.x;
    const int rbase = blockIdx.x * 64;

    // stage waT (bf16, already transposed): 16384 elems = 2048 chunks of 8
    #pragma unroll
    for (int i = 0; i < 8; ++i) {
        const int f = tid + i * 256;
        const int r = f >> 4;              // 0..127
        const int c8 = f & 15;
        *(ushort8*)&wsm[r][c8 * 8] = *(const ushort8*)&waT[r * D + c8 * 8];
    }
    // stage x rows (f32 -> bf16): 8192 elems = 1024 chunks of 8
    #pragma unroll
    for (int i = 0; i < 4; ++i) {
        const int f = tid + i * 256;
        const int r = f >> 4;              // 0..63
        const int c8 = f & 15;
        int rg = rbase + r;
        if (rg > NNODES - 1) rg = NNODES - 1;
        const float4 v0 = *(const float4*)&x[(size_t)rg * D + c8 * 8];
        const float4 v1 = *(const float4*)&x[(size_t)rg * D + c8 * 8 + 4];
        ushort8 o;
        o[0] = f32_to_bf16(v0.x); o[1] = f32_to_bf16(v0.y);
        o[2] = f32_to_bf16(v0.z); o[3] = f32_to_bf16(v0.w);
        o[4] = f32_to_bf16(v1.x); o[5] = f32_to_bf16(v1.y);
        o[6] = f32_to_bf16(v1.z); o[7] = f32_to_bf16(v1.w);
        *(ushort8*)&xs[r][c8 * 8] = o;
    }
    __syncthreads();

    const int lane = tid & 63;
    const int wv = tid >> 6;          // wave -> rows wv*16..+15
    const int r16 = lane & 15;
    const int kg = lane >> 4;         // 0..3

    f32x4 acc[8];
    #pragma unroll
    for (int ct = 0; ct < 8; ++ct) acc[ct] = (f32x4){0.f, 0.f, 0.f, 0.f};

    #pragma unroll
    for (int kq = 0; kq < 4; ++kq) {
        const int ko = kq * 32 + kg * 8;
        const bf16x8 a = *(const bf16x8*)&xs[wv * 16 + r16][ko];
        #pragma unroll
        for (int ct = 0; ct < 8; ++ct) {
            const bf16x8 b = *(const bf16x8*)&wsm[ct * 16 + r16][ko];
            acc[ct] = __builtin_amdgcn_mfma_f32_16x16x32_bf16(a, b, acc[ct], 0, 0, 0);
        }
    }

    #pragma unroll
    for (int ct = 0; ct < 8; ++ct) {
        #pragma unroll
        for (int reg = 0; reg < 4; ++reg) {
            const int row = rbase + wv * 16 + kg * 4 + reg;
            if (row < NNODES)
                y1[(size_t)row * D + ct * 16 + r16] = f32_to_bf16(acc[ct][reg]);
        }
    }
}

// ---------------------------------------------------------------------------
#define ACC8(q)                                                        \
    do {                                                               \
        a[0] += __uint_as_float((q).x << 16);                          \
        a[1] += __uint_as_float((q).x & 0xffff0000u);                  \
        a[2] += __uint_as_float((q).y << 16);                          \
        a[3] += __uint_as_float((q).y & 0xffff0000u);                  \
        a[4] += __uint_as_float((q).z << 16);                          \
        a[5] += __uint_as_float((q).z & 0xffff0000u);                  \
        a[6] += __uint_as_float((q).w << 16);                          \
        a[7] += __uint_as_float((q).w & 0xffff0000u);                  \
    } while (0)

// Fused: h1 = relu(mean_agg(y1)+ba) -> LDS (f32); y2 = bf16(h1 @ W2)
// block = 256 thr = 16 nodes x 16 lanes. LDS 16.9KB -> 8 blocks/CU (wave cap)
__global__ void gather1_gemm2_kernel(const uint4* __restrict__ y1,
                                     const int* __restrict__ rowstart,
                                     const unsigned short* __restrict__ ebuf,
                                     const float* __restrict__ ba,
                                     const float* __restrict__ W2,
                                     unsigned short* __restrict__ y2) {
    __shared__ float h1s[NPB][132];   // reads are nloc-broadcast: conflict-free
    __shared__ float w2s[16][132];    // float4 reads: 2-way aliasing = free (m136)
    const int tid = threadIdx.x;
    const int nloc = tid >> 4;        // 0..15
    const int sub = tid & 15;         // 0..15
    const int node = blockIdx.x * NPB + nloc;

    // ---- phase 1: gather + mean + bias + relu -> h1s (f32) ----
    const int beg = rowstart[node];
    const int cnt = rowstart[node + 1] - beg;
    float a[8];
    {
        const uint4 q = y1[(size_t)node * 16 + sub];   // self loop
        a[0] = __uint_as_float(q.x << 16);  a[1] = __uint_as_float(q.x & 0xffff0000u);
        a[2] = __uint_as_float(q.y << 16);  a[3] = __uint_as_float(q.y & 0xffff0000u);
        a[4] = __uint_as_float(q.z << 16);  a[5] = __uint_as_float(q.z & 0xffff0000u);
        a[6] = __uint_as_float(q.w << 16);  a[7] = __uint_as_float(q.w & 0xffff0000u);
    }
    const unsigned short* nb = ebuf + beg;
    int k = 0;
    for (; k + 8 <= cnt; k += 8) {
        int s[8];
        #pragma unroll
        for (int i = 0; i < 8; ++i) s[i] = nb[k + i];
        uint4 q[8];
        #pragma unroll
        for (int i = 0; i < 8; ++i) q[i] = y1[(size_t)s[i] * 16 + sub];
        #pragma unroll
        for (int i = 0; i < 8; ++i) ACC8(q[i]);
    }
    for (; k < cnt; ++k) {
        const uint4 q = y1[(size_t)nb[k] * 16 + sub];
        ACC8(q);
    }
    const float inv = 1.0f / (float)(cnt + 1);
    #pragma unroll
    for (int j = 0; j < 8; ++j)
        h1s[nloc][sub * 8 + j] = fmaxf(fmaf(a[j], inv, ba[sub * 8 + j]), 0.0f);

    // ---- phase 2: y2 = h1 @ W2 in four 16-col quarters ----
    for (int q = 0; q < 4; ++q) {
        __syncthreads();              // h1s ready / previous quarter consumed
        #pragma unroll
        for (int i = 0; i < 2; ++i) {
            const int f = tid + i * 256;      // 512 float4 slots = 128 rows x 4
            const int kk = f >> 2;            // 0..127
            const int c4 = f & 3;             // 0..3
            const float4 w = *(const float4*)&W2[kk * DOUT + q * 16 + c4 * 4];
            w2s[c4 * 4 + 0][kk] = w.x;
            w2s[c4 * 4 + 1][kk] = w.y;
            w2s[c4 * 4 + 2][kk] = w.z;
            w2s[c4 * 4 + 3][kk] = w.w;
        }
        __syncthreads();
        float acc0 = 0.0f;
        #pragma unroll
        for (int kk = 0; kk < D; kk += 4) {
            const float4 hv = *(const float4*)&h1s[nloc][kk];
            const float4 w0 = *(const float4*)&w2s[sub][kk];
            acc0 = fmaf(hv.x, w0.x, fmaf(hv.y, w0.y, fmaf(hv.z, w0.z, fmaf(hv.w, w0.w, acc0))));
        }
        y2[(size_t)node * DOUT + q * 16 + sub] = f32_to_bf16(acc0);
    }
}

// out = rownorm(mean_agg(y2) + b2): 8 lanes/node, 8-deep load pipeline
__global__ void gather2_kernel(const uint4* __restrict__ y2, const int* __restrict__ rowstart,
                               const unsigned short* __restrict__ ebuf,
                               const float* __restrict__ b2, float* __restrict__ out) {
    const int gid = blockIdx.x * blockDim.x + threadIdx.x;
    const int node = gid >> 3;
    const int sub = gid & 7;
    if (node >= NNODES) return;
    const int beg = rowstart[node];
    const int cnt = rowstart[node + 1] - beg;
    float a[8];
    {
        const uint4 q = y2[(size_t)node * 8 + sub];
        a[0] = __uint_as_float(q.x << 16);  a[1] = __uint_as_float(q.x & 0xffff0000u);
        a[2] = __uint_as_float(q.y << 16);  a[3] = __uint_as_float(q.y & 0xffff0000u);
        a[4] = __uint_as_float(q.z << 16);  a[5] = __uint_as_float(q.z & 0xffff0000u);
        a[6] = __uint_as_float(q.w << 16);  a[7] = __uint_as_float(q.w & 0xffff0000u);
    }
    const unsigned short* nb = ebuf + beg;
    int k = 0;
    for (; k + 8 <= cnt; k += 8) {
        int s[8];
        #pragma unroll
        for (int i = 0; i < 8; ++i) s[i] = nb[k + i];
        uint4 q[8];
        #pragma unroll
        for (int i = 0; i < 8; ++i) q[i] = y2[(size_t)s[i] * 8 + sub];
        #pragma unroll
        for (int i = 0; i < 8; ++i) ACC8(q[i]);
    }
    for (; k < cnt; ++k) {
        const uint4 q = y2[(size_t)nb[k] * 8 + sub];
        ACC8(q);
    }
    const float inv = 1.0f / (float)(cnt + 1);
    float v[8];
    float ss = 0.0f;
    #pragma unroll
    for (int j = 0; j < 8; ++j) {
        v[j] = fmaf(a[j], inv, b2[sub * 8 + j]);
        ss = fmaf(v[j], v[j], ss);
    }
    ss += __shfl_xor(ss, 1);
    ss += __shfl_xor(ss, 2);
    ss += __shfl_xor(ss, 4);
    const float scale = 1.0f / fmaxf(sqrtf(ss), 1e-12f);
    float o[8];
    #pragma unroll
    for (int j = 0; j < 8; ++j) o[j] = v[j] * scale;
    float* dst = &out[(size_t)node * DOUT + sub * 8];
    *(float4*)&dst[0] = *(const float4*)&o[0];
    *(float4*)&dst[4] = *(const float4*)&o[4];
}

// ---------------------------------------------------------------------------
extern "C" void kernel_launch(void* const* d_in, const int* in_sizes, int n_in,
                              void* d_out, int out_size, void* d_ws, size_t ws_size,
                              hipStream_t stream) {
    const float* x    = (const float*)d_in[0];
    const int*   ei   = (const int*)d_in[1];
    const float* Wpre = (const float*)d_in[2];
    const float* bpre = (const float*)d_in[3];
    const float* W1   = (const float*)d_in[4];
    const float* b1   = (const float*)d_in[5];
    const float* W2   = (const float*)d_in[6];
    const float* b2   = (const float*)d_in[7];
    float* out = (float*)d_out;

    // workspace layout (~25.5 MB)
    char* ws = (char*)d_ws;
    unsigned short* y1   = (unsigned short*)ws;                 // [N*128] bf16 = 12.8 MB
    unsigned short* y2   = (unsigned short*)(ws + 12800000);    // [N*64]  bf16 = 6.4 MB
    int* deg             = (int*)(ws + 19200000);               // [50176]
    int* rowstart        = (int*)(ws + 19400704);               // [50176] (N+1 used)
    unsigned short* ebuf = (unsigned short*)(ws + 19601408);    // [E] ushort = 1.6 MB
    unsigned int* bins   = (unsigned int*)(ws + 21201408);      // [NBUCK*BCAP] = 4.0 MB
    int* bcursor         = (int*)(ws + 25205248);               // [NBUCK]
    int* excl            = (int*)(ws + 25207296);               // [SCAN_BLOCKS*256]
    int* partials        = (int*)(ws + 25408000);               // [256]
    int* blockbase       = (int*)(ws + 25409024);               // [256]
    unsigned short* waT  = (unsigned short*)(ws + 25410048);    // [128*128] bf16 = 32 KB
    float* ba            = (float*)(ws + 25442816);             // [128]

    // binned CSR build (no random-scatter passes)
    binit_kernel<<<2, 256, 0, stream>>>(bcursor);
    bin_kernel<<<(NEDGES + CH - 1) / CH, 256, 0, stream>>>(ei, bcursor, bins);
    count_kernel<<<NBUCK, 256, 0, stream>>>(bins, bcursor, deg);
    scan_part1<<<SCAN_BLOCKS, 256, 0, stream>>>(deg, excl, partials);
    scan_part2<<<1, 256, 0, stream>>>(partials, blockbase);
    scan_part3<<<SCAN_BLOCKS, 256, 0, stream>>>(excl, blockbase, rowstart);
    place_kernel<<<NBUCK, 256, 0, stream>>>(bins, bcursor, rowstart, ebuf);

    // folded weights (waT emitted transposed bf16 for MFMA B-operand)
    combine_w_kernel<<<D + 1, D, 0, stream>>>(Wpre, bpre, W1, b1, waT, ba);

    // layer 1: y1 = bf16(x @ Wa) via MFMA
    gemm_y1_mfma<<<(NNODES + 63) / 64, 256, 0, stream>>>(x, waT, y1);

    // fused: h1 = relu(mean_agg(y1)+ba) in LDS; y2 = bf16(h1 @ W2)
    gather1_gemm2_kernel<<<NNODES / NPB, 256, 0, stream>>>(
        (const uint4*)y1, rowstart, ebuf, ba, W2, y2);

    // layer 2 aggregate + normalize
    gather2_kernel<<<(NNODES * 8 + 255) / 256, 256, 0, stream>>>(
        (const uint4*)y2, rowstart, ebuf, b2, out);
}